// Round 2
// baseline (17554.468 us; speedup 1.0000x reference)
//
#include <hip/hip_runtime.h>
#include <math.h>

typedef _Float16 f16;
typedef _Float16 half8 __attribute__((ext_vector_type(8)));
typedef _Float16 half4v __attribute__((ext_vector_type(4)));
typedef float f32x4 __attribute__((ext_vector_type(4)));

#define BATCH 8192
#define SDIM  1024
#define HDIM  2048
#define DECD  1024
#define EMBD  256
#define G3    3072
#define VOCAB 169
#define TLEN  20
#define SOS_TOK 166
#define IGN_TOK 168
#define OUTC  166

#define GLOAD16(gp, lp) __builtin_amdgcn_global_load_lds( \
    (const __attribute__((address_space(1))) unsigned int*)(gp), \
    (__attribute__((address_space(3))) unsigned int*)(lp), 16, 0, 0)

// fp16x2 split: a ~= hi + lo/2048, avoids fp16-subnormal hi for tiny a
__device__ __forceinline__ void split2(float a, f16& h, f16& l)
{
    float hi = (fabsf(a) >= 6.103515625e-05f) ? (float)(f16)a : 0.0f;
    h = (f16)hi;
    l = (f16)((a - hi) * 2048.0f);
}

// LDS tile layout (A and B identical): logical (r in [0,128), k in [0,32)).
// 128B "lines" hold row pairs; 16B slots XOR-swizzled by line&7 so that
// ds_read_b128 fragment reads are 2-way (free) bank accesses.
__device__ __forceinline__ int swz(int r, int k0)   // halfword offset
{
    const int line = r >> 1;
    const int s = (((r & 1) << 2) | (k0 >> 3)) ^ (line & 7);
    return line * 64 + s * 8;
}

// ============ fp16x2 3-pass MFMA GEMM: C = op(A[M,K] @ Bt[N,K]^T + bias) ============
// MODE bit0: write fp32 C; bit1: write split (Ch, Cl)
template<int MODE>
__global__ __launch_bounds__(256, 2)
void gemm16(const f16* __restrict__ Ah, const f16* __restrict__ Al,
            const f16* __restrict__ Bh, const f16* __restrict__ Bl,
            const float* __restrict__ bias, float* __restrict__ C,
            f16* __restrict__ Ch, f16* __restrict__ Cl,
            int M, int N, int K, int relu)
{
    __shared__ __align__(16) f16 lds[4][4096];   // Ahi, Alo, Bhi, Blo (8KB each)

    const int nx = N >> 7;
    const int cpx = gridDim.x >> 3;              // grids are %8==0
    int wg = blockIdx.x;
    wg = (wg & 7) * cpx + (wg >> 3);             // XCD-aware swizzle
    const int m0 = (wg / nx) << 7;
    const int n0 = (wg % nx) << 7;

    const int tid = threadIdx.x;
    const int w = tid >> 6;
    const int lane = tid & 63;
    const int wr = w >> 1, wc = w & 1;

    // staging: per-lane global source offset implementing the LDS swizzle
    const int qq = (lane & 7) ^ (lane >> 3);
    const int row_off = ((lane >> 3) << 1) | (qq >> 2);
    const int k_off = (qq & 3) << 3;
    const f16* sb = (w == 0) ? Ah + (size_t)m0 * K
                  : (w == 1) ? Al + (size_t)m0 * K
                  : (w == 2) ? Bh + (size_t)n0 * K
                             : Bl + (size_t)n0 * K;
    sb += (size_t)row_off * K + k_off;
    f16* lb = &lds[w][0];

    // fragment ds_read offsets (constant across K-steps)
    int offA[4], offB[4];
    {
        const int fr = lane & 15, k0 = (lane >> 4) << 3;
#pragma unroll
        for (int t = 0; t < 4; ++t) {
            offA[t] = swz(wr * 64 + t * 16 + fr, k0);
            offB[t] = swz(wc * 64 + t * 16 + fr, k0);
        }
    }

    f32x4 acch[4][4], accl[4][4];
#pragma unroll
    for (int i = 0; i < 4; ++i)
#pragma unroll
        for (int j = 0; j < 4; ++j) { acch[i][j] = (f32x4)0.0f; accl[i][j] = (f32x4)0.0f; }

    const int nkt = K >> 5;
    const size_t K16 = (size_t)K * 16;
    for (int kt = 0; kt < nkt; ++kt) {
        const f16* s = sb + kt * 32;
#pragma unroll
        for (int i = 0; i < 8; ++i)
            GLOAD16(s + (size_t)i * K16, lb + i * 512);
        __syncthreads();

        half8 fah[4], fbh[4], fal[4], fbl[4];
#pragma unroll
        for (int t = 0; t < 4; ++t) {
            fah[t] = *(const half8*)&lds[0][offA[t]];
            fal[t] = *(const half8*)&lds[1][offA[t]];
            fbh[t] = *(const half8*)&lds[2][offB[t]];
            fbl[t] = *(const half8*)&lds[3][offB[t]];
        }
#pragma unroll
        for (int i = 0; i < 4; ++i)
#pragma unroll
            for (int j = 0; j < 4; ++j) {
                acch[i][j] = __builtin_amdgcn_mfma_f32_16x16x32_f16(fah[i], fbh[j], acch[i][j], 0, 0, 0);
                accl[i][j] = __builtin_amdgcn_mfma_f32_16x16x32_f16(fal[i], fbh[j], accl[i][j], 0, 0, 0);
                accl[i][j] = __builtin_amdgcn_mfma_f32_16x16x32_f16(fah[i], fbl[j], accl[i][j], 0, 0, 0);
            }
        __syncthreads();
    }

    // epilogue: C/D layout col=lane&15, row=(lane>>4)*4+reg
    const float inv2048 = 4.8828125e-4f;
    const int fr = lane & 15;
    const int fq = lane >> 4;
#pragma unroll
    for (int j = 0; j < 4; ++j) {
        const int col = n0 + wc * 64 + j * 16 + fr;
        const float bc = bias[col];
#pragma unroll
        for (int i = 0; i < 4; ++i) {
            const int row0 = m0 + wr * 64 + i * 16 + fq * 4;
            const f32x4 vh = acch[i][j], vl = accl[i][j];
#pragma unroll
            for (int r = 0; r < 4; ++r) {
                float v = vh[r] + vl[r] * inv2048 + bc;
                if (relu) v = fmaxf(v, 0.0f);
                const size_t o = (size_t)(row0 + r) * N + col;
                if constexpr (MODE & 1) C[o] = v;
                if constexpr (MODE & 2) { f16 hh, hl; split2(v, hh, hl); Ch[o] = hh; Cl[o] = hl; }
            }
        }
    }
}

// ============ weight transpose + split: W[K][N] -> Wt_hi/lo [N][K] ============
__global__ __launch_bounds__(256)
void transpose_split(const float* __restrict__ Wm, f16* __restrict__ th, f16* __restrict__ tl,
                     int K, int N)
{
    __shared__ float tile[32][33];
    const int n0 = blockIdx.x << 5, k0 = blockIdx.y << 5;
    const int tx = threadIdx.x & 31, ty = threadIdx.x >> 5;
#pragma unroll
    for (int j = 0; j < 32; j += 8)
        tile[ty + j][tx] = Wm[(size_t)(k0 + ty + j) * N + n0 + tx];
    __syncthreads();
#pragma unroll
    for (int j = 0; j < 32; j += 8) {
        const float a = tile[tx][ty + j];
        f16 hh, hl; split2(a, hh, hl);
        const size_t o = (size_t)(n0 + ty + j) * K + k0 + tx;
        th[o] = hh; tl[o] = hl;
    }
}

// ============ activation split (s input) ============
__global__ __launch_bounds__(256)
void split_act(const float* __restrict__ x, f16* __restrict__ xh, f16* __restrict__ xl)
{
    const int i = blockIdx.x * 256 + threadIdx.x;
    const float4 v = ((const float4*)x)[i];
    half4v hh, hl;
#pragma unroll
    for (int c = 0; c < 4; ++c) { f16 a, b; split2((&v.x)[c], a, b); hh[c] = a; hl[c] = b; }
    ((half4v*)xh)[i] = hh;
    ((half4v*)xl)[i] = hl;
}

// ---------------- tokgi[v] = emb[v] @ Wih[0:256, :]  ([169, 3072]) ----------------
__global__ __launch_bounds__(256)
void tok_gi(const float* __restrict__ emb, const float* __restrict__ Wih,
            float* __restrict__ tg)
{
    __shared__ float es[EMBD];
    const int v = blockIdx.y;
    const int n = blockIdx.x * 256 + threadIdx.x;
    es[threadIdx.x] = emb[(size_t)v * EMBD + threadIdx.x];
    __syncthreads();
    float s = 0.f;
#pragma unroll 8
    for (int k = 0; k < EMBD; ++k)
        s = fmaf(es[k], Wih[(size_t)k * G3 + n], s);
    tg[(size_t)v * G3 + n] = s;
}

// ---------------- GRU gates (vectorized, in-place h update + fp16x2 split) ----------------
__global__ __launch_bounds__(256)
void gru_gates(const float* __restrict__ gh, const float* __restrict__ gx0,
               const float* __restrict__ tokgi, const int* __restrict__ tseq,
               int t, float* __restrict__ hio, f16* __restrict__ hh_out, f16* __restrict__ hl_out)
{
    const int i4 = blockIdx.x * 256 + threadIdx.x;
    const int b  = i4 >> 8;
    const int j  = (i4 & 255) << 2;
    const int tok = (t == 0) ? SOS_TOK : tseq[(size_t)b * TLEN + (t - 1)];
    const size_t gb = (size_t)b * G3;
    const size_t tb = (size_t)tok * G3;

    const float4 tr = *(const float4*)&tokgi[tb + j];
    const float4 tz = *(const float4*)&tokgi[tb + 1024 + j];
    const float4 tn = *(const float4*)&tokgi[tb + 2048 + j];
    const float4 xr = *(const float4*)&gx0[gb + j];
    const float4 xz = *(const float4*)&gx0[gb + 1024 + j];
    const float4 xn = *(const float4*)&gx0[gb + 2048 + j];
    const float4 hr = *(const float4*)&gh[gb + j];
    const float4 hz = *(const float4*)&gh[gb + 1024 + j];
    const float4 hn = *(const float4*)&gh[gb + 2048 + j];
    const size_t hidx = (size_t)b * DECD + j;
    const float4 hp = *(const float4*)&hio[hidx];

    float4 ho;
    half4v sh, sl;
#pragma unroll
    for (int c = 0; c < 4; ++c) {
        const float r = 1.f / (1.f + expf(-((&tr.x)[c] + (&xr.x)[c] + (&hr.x)[c])));
        const float z = 1.f / (1.f + expf(-((&tz.x)[c] + (&xz.x)[c] + (&hz.x)[c])));
        const float n = tanhf((&tn.x)[c] + (&xn.x)[c] + r * (&hn.x)[c]);
        const float hv = (1.f - z) * n + z * (&hp.x)[c];
        (&ho.x)[c] = hv;
        f16 a, bb; split2(hv, a, bb); sh[c] = a; sl[c] = bb;
    }
    *(float4*)&hio[hidx] = ho;
    if (hh_out) {
        *(half4v*)&hh_out[hidx] = sh;
        *(half4v*)&hl_out[hidx] = sl;
    }
}

// ---------------- fused logits + argmax + CE (fp32, unchanged from R1) ----------------
#define LROWS 16
#define LKC   256

__global__ __launch_bounds__(256, 2)
void logits_kernel(const float* __restrict__ h, const float* __restrict__ Wp,
                   const float* __restrict__ bp, const int* __restrict__ tseq,
                   int t, float* __restrict__ pred, float* __restrict__ accb)
{
    __shared__ float hs[LROWS][LKC];
    const int tid  = threadIdx.x;
    const int lane = tid & 63;
    const int wv   = tid >> 6;
    const int b0   = blockIdx.x * LROWS;
    const bool v2  = (lane < VOCAB - 128);

    float acc0[4], acc1[4], acc2[4];
#pragma unroll
    for (int r = 0; r < 4; ++r) { acc0[r] = 0.f; acc1[r] = 0.f; acc2[r] = 0.f; }

    const int r0 = wv * 4;
    for (int kc = 0; kc < DECD; kc += LKC) {
        __syncthreads();
#pragma unroll
        for (int j = 0; j < 4; ++j) {
            const int f = tid + j * 256;
            const int row = f >> 6, c4 = f & 63;
            *reinterpret_cast<float4*>(&hs[row][c4*4]) =
                *reinterpret_cast<const float4*>(&h[(size_t)(b0+row)*DECD + kc + c4*4]);
        }
        __syncthreads();
        for (int k4 = 0; k4 < LKC/4; ++k4) {
            float4 hv[4];
#pragma unroll
            for (int r = 0; r < 4; ++r)
                hv[r] = *reinterpret_cast<const float4*>(&hs[r0+r][k4*4]);
#pragma unroll
            for (int kk = 0; kk < 4; ++kk) {
                const int kg = kc + k4*4 + kk;
                const float w0 = Wp[(size_t)kg*VOCAB + lane];
                const float w1 = Wp[(size_t)kg*VOCAB + lane + 64];
                const float w2 = v2 ? Wp[(size_t)kg*VOCAB + lane + 128] : 0.f;
#pragma unroll
                for (int r = 0; r < 4; ++r) {
                    const float hrk = (&hv[r].x)[kk];
                    acc0[r] = fmaf(hrk, w0, acc0[r]);
                    acc1[r] = fmaf(hrk, w1, acc1[r]);
                    acc2[r] = fmaf(hrk, w2, acc2[r]);
                }
            }
        }
    }

    float wnll = 0.f, wcnt = 0.f;
    for (int r = 0; r < 4; ++r) {
        const int b = b0 + r0 + r;
        const float l0 = acc0[r] + bp[lane];
        const float l1 = acc1[r] + bp[lane + 64];
        const float l2 = v2 ? (acc2[r] + bp[lane + 128]) : 0.f;
        float m = l0; int mi = lane;
        if (l1 > m) { m = l1; mi = lane + 64; }
        if (v2 && l2 > m) { m = l2; mi = lane + 128; }
#pragma unroll
        for (int off = 32; off >= 1; off >>= 1) {
            const float om = __shfl_xor(m, off);
            const int   oi = __shfl_xor(mi, off);
            if (om > m || (om == m && oi < mi)) { m = om; mi = oi; }
        }
        const int tgt = tseq[(size_t)b * TLEN + t];
        float se = expf(l0 - m) + expf(l1 - m) + (v2 ? expf(l2 - m) : 0.f);
        const int ts = tgt >> 6, tl_lane = tgt & 63;
        float tl = (lane == tl_lane) ? ((ts == 0) ? l0 : (ts == 1) ? l1 : l2) : 0.f;
#pragma unroll
        for (int off = 32; off >= 1; off >>= 1) {
            se += __shfl_xor(se, off);
            tl += __shfl_xor(tl, off);
        }
        if (lane == 0) {
            if (mi < OUTC) pred[(size_t)b * OUTC + mi] = 1.0f;
            if (tgt != IGN_TOK) { wnll += (m + logf(se)) - tl; wcnt += 1.f; }
        }
    }
    if (lane == 0) {
        atomicAdd(&accb[0], wnll);
        atomicAdd(&accb[1], wcnt);
    }
}

__global__ void finalize_loss(const float* __restrict__ accb, float* __restrict__ out)
{
    out[0] = accb[0] / fmaxf(accb[1], 1.f);
}

// ============ fallback fp32 GEMM (round-1 path, used only if ws too small) ============
#define BM  128
#define BN  128
#define BKK 16
#define LDS_A (BM + 4)
#define LDS_B (BN + 4)

__global__ __launch_bounds__(256, 2)
void gemm_f32(const float* __restrict__ A, const float* __restrict__ Bm,
              const float* __restrict__ bias, float* __restrict__ C,
              int M, int N, int K, int do_relu)
{
    __shared__ float As[BKK][LDS_A];
    __shared__ float Bs[BKK][LDS_B];
    const int tid = threadIdx.x;
    const int m0 = blockIdx.y * BM;
    const int n0 = blockIdx.x * BN;
    const int ty = tid >> 4;
    const int tx = tid & 15;

    float acc[8][8];
#pragma unroll
    for (int i = 0; i < 8; ++i)
#pragma unroll
        for (int j = 0; j < 8; ++j) acc[i][j] = 0.f;

    const int arow = tid >> 2;
    const int akq  = tid & 3;
    const int bkr  = tid >> 5;
    const int bnq  = tid & 31;

    for (int k0 = 0; k0 < K; k0 += BKK) {
#pragma unroll
        for (int h = 0; h < 2; ++h) {
            const int row = arow + h * 64;
            float4 av = *reinterpret_cast<const float4*>(&A[(size_t)(m0 + row) * K + k0 + akq * 4]);
            As[akq*4+0][row] = av.x; As[akq*4+1][row] = av.y;
            As[akq*4+2][row] = av.z; As[akq*4+3][row] = av.w;
        }
#pragma unroll
        for (int h = 0; h < 2; ++h) {
            const int kr = bkr + h * 8;
            float4 bv = *reinterpret_cast<const float4*>(&Bm[(size_t)(k0 + kr) * N + n0 + bnq * 4]);
            *reinterpret_cast<float4*>(&Bs[kr][bnq * 4]) = bv;
        }
        __syncthreads();
#pragma unroll
        for (int kk = 0; kk < BKK; ++kk) {
            float a[8], b[8];
            *reinterpret_cast<float4*>(&a[0]) = *reinterpret_cast<const float4*>(&As[kk][ty*8]);
            *reinterpret_cast<float4*>(&a[4]) = *reinterpret_cast<const float4*>(&As[kk][ty*8+4]);
            *reinterpret_cast<float4*>(&b[0]) = *reinterpret_cast<const float4*>(&Bs[kk][tx*8]);
            *reinterpret_cast<float4*>(&b[4]) = *reinterpret_cast<const float4*>(&Bs[kk][tx*8+4]);
#pragma unroll
            for (int i = 0; i < 8; ++i)
#pragma unroll
                for (int j = 0; j < 8; ++j)
                    acc[i][j] = fmaf(a[i], b[j], acc[i][j]);
        }
        __syncthreads();
    }

#pragma unroll
    for (int i = 0; i < 8; ++i) {
        const int gm = m0 + ty * 8 + i;
#pragma unroll
        for (int jj = 0; jj < 2; ++jj) {
            const int gn = n0 + tx * 8 + jj * 4;
            float4 o; float* op = &o.x;
#pragma unroll
            for (int j = 0; j < 4; ++j) {
                float v = acc[i][jj*4+j] + bias[gn + j];
                if (do_relu) v = fmaxf(v, 0.f);
                op[j] = v;
            }
            *reinterpret_cast<float4*>(&C[(size_t)gm * N + gn]) = o;
        }
    }
}

extern "C" void kernel_launch(void* const* d_in, const int* in_sizes, int n_in,
                              void* d_out, int out_size, void* d_ws, size_t ws_size,
                              hipStream_t stream)
{
    const float* s    = (const float*)d_in[0];
    const int*   aseq = (const int*)  d_in[1];
    const float* W1   = (const float*)d_in[2];
    const float* b1   = (const float*)d_in[3];
    const float* W2   = (const float*)d_in[4];
    const float* b2   = (const float*)d_in[5];
    const float* emb  = (const float*)d_in[6];
    const float* Wih  = (const float*)d_in[7];
    const float* Whh  = (const float*)d_in[8];
    const float* bih  = (const float*)d_in[9];
    const float* bhh  = (const float*)d_in[10];
    const float* Wp   = (const float*)d_in[11];
    const float* bp   = (const float*)d_in[12];
    float* outp = (float*)d_out;
    char* W = (char*)d_ws;

    // byte sizes
    const size_t SZ_GH  = (size_t)BATCH * G3 * 4;      // 100663296
    const size_t SZ_H   = (size_t)BATCH * DECD * 4;    // 33554432
    const size_t SZ_HS  = (size_t)BATCH * DECD * 2;    // 16777216
    const size_t SZ_TG  = (size_t)VOCAB * G3 * 4;      // 2076672
    const size_t SZ_W1T = (size_t)SDIM * HDIM * 2;     // 4194304
    const size_t SZ_W2T = (size_t)HDIM * DECD * 2;
    const size_t SZ_WIT = (size_t)DECD * G3 * 2;       // 6291456

    const size_t o_gh  = 0;
    const size_t o_gx0 = o_gh  + SZ_GH;
    const size_t o_h   = o_gx0 + SZ_GH;
    const size_t o_hh  = o_h   + SZ_H;
    const size_t o_hl  = o_hh  + SZ_HS;
    const size_t o_tg  = o_hl  + SZ_HS;
    const size_t o_w1h = o_tg  + SZ_TG;
    const size_t o_w1l = o_w1h + SZ_W1T;
    const size_t o_w2h = o_w1l + SZ_W1T;
    const size_t o_w2l = o_w2h + SZ_W2T;
    const size_t o_wih = o_w2l + SZ_W2T;
    const size_t o_wil = o_wih + SZ_WIT;
    const size_t o_whh = o_wil + SZ_WIT;
    const size_t o_whl = o_whh + SZ_WIT;
    const size_t o_acc = o_whl + SZ_WIT;
    const size_t need  = o_acc + 256;

    hipMemsetAsync(d_out, 0, (size_t)out_size * sizeof(float), stream);

    if (ws_size >= need) {
        // ---------------- fp16x2 MFMA path ----------------
        float* gh   = (float*)(W + o_gh);
        float* gx0  = (float*)(W + o_gx0);
        float* hbuf = (float*)(W + o_h);
        f16*   hh   = (f16*)(W + o_hh);
        f16*   hl   = (f16*)(W + o_hl);
        float* tg   = (float*)(W + o_tg);
        f16 *w1h = (f16*)(W + o_w1h), *w1l = (f16*)(W + o_w1l);
        f16 *w2h = (f16*)(W + o_w2h), *w2l = (f16*)(W + o_w2l);
        f16 *wih = (f16*)(W + o_wih), *wil = (f16*)(W + o_wil);
        f16 *whh = (f16*)(W + o_whh), *whl = (f16*)(W + o_whl);
        float* accb = (float*)(W + o_acc);
        // aliases (transients inside gh / gx0 regions)
        f16* h1h = (f16*)(W + o_gh);                               // 8192x2048 halves
        f16* h1l = (f16*)(W + o_gh + (size_t)BATCH * HDIM * 2);
        f16* sh  = (f16*)(W + o_gx0);                              // 8192x1024 halves
        f16* sl  = (f16*)(W + o_gx0 + (size_t)BATCH * SDIM * 2);

        hipMemsetAsync(accb, 0, 2 * sizeof(float), stream);

        // one-time per launch: splits + transposes
        split_act<<<dim3(BATCH * SDIM / 4 / 256), 256, 0, stream>>>(s, sh, sl);
        transpose_split<<<dim3(HDIM/32, SDIM/32), 256, 0, stream>>>(W1, w1h, w1l, SDIM, HDIM);
        transpose_split<<<dim3(DECD/32, HDIM/32), 256, 0, stream>>>(W2, w2h, w2l, HDIM, DECD);
        transpose_split<<<dim3(G3/32, DECD/32), 256, 0, stream>>>(Wih + (size_t)EMBD * G3, wih, wil, DECD, G3);
        transpose_split<<<dim3(G3/32, DECD/32), 256, 0, stream>>>(Whh, whh, whl, DECD, G3);
        tok_gi<<<dim3(G3/256, VOCAB), 256, 0, stream>>>(emb, Wih, tg);

        // encoder: h1 = relu(s@W1+b1) [split only]; h0 = h1@W2+b2 [f32 + split]
        gemm16<2><<<dim3((BATCH/128)*(HDIM/128)), 256, 0, stream>>>(
            sh, sl, w1h, w1l, b1, nullptr, h1h, h1l, BATCH, HDIM, SDIM, 1);
        gemm16<3><<<dim3((BATCH/128)*(DECD/128)), 256, 0, stream>>>(
            h1h, h1l, w2h, w2l, b2, hbuf, hh, hl, BATCH, DECD, HDIM, 0);
        // gx0 = h0 @ Wih[256:,:] + bih
        gemm16<1><<<dim3((BATCH/128)*(G3/128)), 256, 0, stream>>>(
            hh, hl, wih, wil, bih, gx0, nullptr, nullptr, BATCH, G3, DECD, 0);

        for (int t = 0; t < TLEN; ++t) {
            gemm16<1><<<dim3((BATCH/128)*(G3/128)), 256, 0, stream>>>(
                hh, hl, whh, whl, bhh, gh, nullptr, nullptr, BATCH, G3, DECD, 0);
            gru_gates<<<dim3(BATCH * DECD / 4 / 256), 256, 0, stream>>>(
                gh, gx0, tg, aseq, t, hbuf, hh, hl);
            logits_kernel<<<dim3(BATCH / LROWS), 256, 0, stream>>>(
                hbuf, Wp, bp, aseq, t, outp + 1, accb);
        }
        finalize_loss<<<1, 1, 0, stream>>>(accb, outp);
    } else {
        // ---------------- fallback fp32 path (round-1 layout) ----------------
        float* ws = (float*)d_ws;
        const size_t f_gh    = 0;
        const size_t f_gx0   = (size_t)BATCH * G3;
        const size_t f_h     = f_gx0 + (size_t)BATCH * G3;
        const size_t f_tokgi = f_h + (size_t)BATCH * DECD;
        const size_t f_acc   = f_tokgi + (size_t)VOCAB * G3 + 64;
        if (ws_size < (f_acc + 64) * sizeof(float)) return;

        float* gh   = ws + f_gh;
        float* h1   = ws + f_gh;
        float* gx0  = ws + f_gx0;
        float* hbuf = ws + f_h;
        float* tg   = ws + f_tokgi;
        float* accb = ws + f_acc;

        hipMemsetAsync(accb, 0, 2 * sizeof(float), stream);

        gemm_f32<<<dim3(HDIM/BN, BATCH/BM), 256, 0, stream>>>(s,  W1, b1, h1,   BATCH, HDIM, SDIM, 1);
        gemm_f32<<<dim3(DECD/BN, BATCH/BM), 256, 0, stream>>>(h1, W2, b2, hbuf, BATCH, DECD, HDIM, 0);
        gemm_f32<<<dim3(G3/BN, BATCH/BM), 256, 0, stream>>>(hbuf, Wih + (size_t)EMBD * G3, bih, gx0,
                                                            BATCH, G3, DECD, 0);
        tok_gi<<<dim3(G3/256, VOCAB), 256, 0, stream>>>(emb, Wih, tg);

        for (int t = 0; t < TLEN; ++t) {
            gemm_f32<<<dim3(G3/BN, BATCH/BM), 256, 0, stream>>>(hbuf, Whh, bhh, gh, BATCH, G3, DECD, 0);
            gru_gates<<<dim3(BATCH * DECD / 4 / 256), 256, 0, stream>>>(
                gh, gx0, tg, aseq, t, hbuf, nullptr, nullptr);
            logits_kernel<<<dim3(BATCH / LROWS), 256, 0, stream>>>(
                hbuf, Wp, bp, aseq, t, outp + 1, accb);
        }
        finalize_loss<<<1, 1, 0, stream>>>(accb, outp);
    }
}

// Round 3
// 8223.396 us; speedup vs baseline: 2.1347x; 2.1347x over previous
//
#include <hip/hip_runtime.h>
#include <math.h>

typedef _Float16 f16;
typedef _Float16 half8 __attribute__((ext_vector_type(8)));
typedef _Float16 half4v __attribute__((ext_vector_type(4)));
typedef float f32x4 __attribute__((ext_vector_type(4)));

#define BATCH 8192
#define SDIM  1024
#define HDIM  2048
#define DECD  1024
#define EMBD  256
#define G3    3072
#define VOCAB 169
#define TLEN  20
#define SOS_TOK 166
#define IGN_TOK 168
#define OUTC  166
#define MCHUNK 4096

#define GLOAD16(gp, lp) __builtin_amdgcn_global_load_lds( \
    (const __attribute__((address_space(1))) unsigned int*)(gp), \
    (__attribute__((address_space(3))) unsigned int*)(lp), 16, 0, 0)

// fp16x2 split: a ~= hi + lo/2048, avoids fp16-subnormal hi for tiny a
__device__ __forceinline__ void split2(float a, f16& h, f16& l)
{
    float hi = (fabsf(a) >= 6.103515625e-05f) ? (float)(f16)a : 0.0f;
    h = (f16)hi;
    l = (f16)((a - hi) * 2048.0f);
}

__device__ __forceinline__ float join2(f16 h, f16 l)
{
    return (float)h + (float)l * 4.8828125e-4f;
}

// LDS tile layout (A and B identical): logical (r in [0,128), k in [0,32)).
// 128B "lines" hold row pairs; 16B slots XOR-swizzled by line&7 so that
// ds_read_b128 fragment reads are ~2-way (free) bank accesses.
__device__ __forceinline__ int swz(int r, int k0)   // halfword offset
{
    const int line = r >> 1;
    const int s = (((r & 1) << 2) | (k0 >> 3)) ^ (line & 7);
    return line * 64 + s * 8;
}

// ============ fp16x2 3-pass MFMA GEMM: C = op(A[M,K] @ Bt[N,K]^T + bias) ============
// MODE bit0: write fp32 C; bit1: write split (Ch, Cl)
template<int MODE>
__global__ __launch_bounds__(256, 2)
void gemm16(const f16* __restrict__ Ah, const f16* __restrict__ Al,
            const f16* __restrict__ Bh, const f16* __restrict__ Bl,
            const float* __restrict__ bias, float* __restrict__ C,
            f16* __restrict__ Ch, f16* __restrict__ Cl,
            int M, int N, int K, int relu)
{
    __shared__ __align__(16) f16 lds[4][4096];   // Ahi, Alo, Bhi, Blo (8KB each)

    const int nx = N >> 7;
    const int cpx = gridDim.x >> 3;              // grids are %8==0
    int wg = blockIdx.x;
    wg = (wg & 7) * cpx + (wg >> 3);             // XCD-aware swizzle
    const int m0 = (wg / nx) << 7;
    const int n0 = (wg % nx) << 7;

    const int tid = threadIdx.x;
    const int w = tid >> 6;
    const int lane = tid & 63;
    const int wr = w >> 1, wc = w & 1;

    // staging: per-lane global source offset implementing the LDS swizzle
    const int qq = (lane & 7) ^ (lane >> 3);
    const int row_off = ((lane >> 3) << 1) | (qq >> 2);
    const int k_off = (qq & 3) << 3;
    const f16* sb = (w == 0) ? Ah + (size_t)m0 * K
                  : (w == 1) ? Al + (size_t)m0 * K
                  : (w == 2) ? Bh + (size_t)n0 * K
                             : Bl + (size_t)n0 * K;
    sb += (size_t)row_off * K + k_off;
    f16* lb = &lds[w][0];

    // fragment ds_read offsets (constant across K-steps)
    int offA[4], offB[4];
    {
        const int fr = lane & 15, k0 = (lane >> 4) << 3;
#pragma unroll
        for (int t = 0; t < 4; ++t) {
            offA[t] = swz(wr * 64 + t * 16 + fr, k0);
            offB[t] = swz(wc * 64 + t * 16 + fr, k0);
        }
    }

    f32x4 acch[4][4], accl[4][4];
#pragma unroll
    for (int i = 0; i < 4; ++i)
#pragma unroll
        for (int j = 0; j < 4; ++j) { acch[i][j] = (f32x4)0.0f; accl[i][j] = (f32x4)0.0f; }

    const int nkt = K >> 5;
    const size_t K16 = (size_t)K * 16;
    for (int kt = 0; kt < nkt; ++kt) {
        const f16* s = sb + kt * 32;
#pragma unroll
        for (int i = 0; i < 8; ++i)
            GLOAD16(s + (size_t)i * K16, lb + i * 512);
        __syncthreads();

        half8 fah[4], fbh[4], fal[4], fbl[4];
#pragma unroll
        for (int t = 0; t < 4; ++t) {
            fah[t] = *(const half8*)&lds[0][offA[t]];
            fal[t] = *(const half8*)&lds[1][offA[t]];
            fbh[t] = *(const half8*)&lds[2][offB[t]];
            fbl[t] = *(const half8*)&lds[3][offB[t]];
        }
#pragma unroll
        for (int i = 0; i < 4; ++i)
#pragma unroll
            for (int j = 0; j < 4; ++j) {
                acch[i][j] = __builtin_amdgcn_mfma_f32_16x16x32_f16(fah[i], fbh[j], acch[i][j], 0, 0, 0);
                accl[i][j] = __builtin_amdgcn_mfma_f32_16x16x32_f16(fal[i], fbh[j], accl[i][j], 0, 0, 0);
                accl[i][j] = __builtin_amdgcn_mfma_f32_16x16x32_f16(fah[i], fbl[j], accl[i][j], 0, 0, 0);
            }
        __syncthreads();
    }

    // epilogue: C/D layout col=lane&15, row=(lane>>4)*4+reg
    const float inv2048 = 4.8828125e-4f;
    const int fr = lane & 15;
    const int fq = lane >> 4;
#pragma unroll
    for (int j = 0; j < 4; ++j) {
        const int col = n0 + wc * 64 + j * 16 + fr;
        const float bc = bias[col];
#pragma unroll
        for (int i = 0; i < 4; ++i) {
            const int row0 = m0 + wr * 64 + i * 16 + fq * 4;
            const f32x4 vh = acch[i][j], vl = accl[i][j];
#pragma unroll
            for (int r = 0; r < 4; ++r) {
                float v = vh[r] + vl[r] * inv2048 + bc;
                if (relu) v = fmaxf(v, 0.0f);
                const size_t o = (size_t)(row0 + r) * N + col;
                if constexpr (MODE & 1) C[o] = v;
                if constexpr (MODE & 2) { f16 hh, hl; split2(v, hh, hl); Ch[o] = hh; Cl[o] = hl; }
            }
        }
    }
}

// ============ weight transpose + split: W[K][N] -> Wt_hi/lo [N][K] ============
__global__ __launch_bounds__(256)
void transpose_split(const float* __restrict__ Wm, f16* __restrict__ th, f16* __restrict__ tl,
                     int K, int N)
{
    __shared__ float tile[32][33];
    const int n0 = blockIdx.x << 5, k0 = blockIdx.y << 5;
    const int tx = threadIdx.x & 31, ty = threadIdx.x >> 5;
#pragma unroll
    for (int j = 0; j < 32; j += 8)
        tile[ty + j][tx] = Wm[(size_t)(k0 + ty + j) * N + n0 + tx];
    __syncthreads();
#pragma unroll
    for (int j = 0; j < 32; j += 8) {
        const float a = tile[tx][ty + j];
        f16 hh, hl; split2(a, hh, hl);
        const size_t o = (size_t)(n0 + ty + j) * K + k0 + tx;
        th[o] = hh; tl[o] = hl;
    }
}

// ============ activation split (s input) ============
__global__ __launch_bounds__(256)
void split_act(const float* __restrict__ x, f16* __restrict__ xh, f16* __restrict__ xl)
{
    const int i = blockIdx.x * 256 + threadIdx.x;
    const float4 v = ((const float4*)x)[i];
    half4v hh, hl;
#pragma unroll
    for (int c = 0; c < 4; ++c) { f16 a, b; split2((&v.x)[c], a, b); hh[c] = a; hl[c] = b; }
    ((half4v*)xh)[i] = hh;
    ((half4v*)xl)[i] = hl;
}

// ---------------- tokgi[v] = emb[v] @ Wih[0:256, :]  ([169, 3072]) ----------------
__global__ __launch_bounds__(256)
void tok_gi(const float* __restrict__ emb, const float* __restrict__ Wih,
            float* __restrict__ tg)
{
    __shared__ float es[EMBD];
    const int v = blockIdx.y;
    const int n = blockIdx.x * 256 + threadIdx.x;
    es[threadIdx.x] = emb[(size_t)v * EMBD + threadIdx.x];
    __syncthreads();
    float s = 0.f;
#pragma unroll 8
    for (int k = 0; k < EMBD; ++k)
        s = fmaf(es[k], Wih[(size_t)k * G3 + n], s);
    tg[(size_t)v * G3 + n] = s;
}

// ---------------- GRU gates: h(split) updated in place; gh is chunk-local ----------------
__global__ __launch_bounds__(256)
void gru_gates(const float* __restrict__ gh, const float* __restrict__ gx0,
               const float* __restrict__ tokgi, const int* __restrict__ tseq,
               int t, int b0g, f16* __restrict__ hh, f16* __restrict__ hl)
{
    const int i4 = blockIdx.x * 256 + threadIdx.x;
    const int bl = i4 >> 8;          // chunk-local batch row
    const int b  = b0g + bl;         // global batch row
    const int j  = (i4 & 255) << 2;
    const int tok = (t == 0) ? SOS_TOK : tseq[(size_t)b * TLEN + (t - 1)];
    const size_t gb = (size_t)b * G3;
    const size_t lb = (size_t)bl * G3;
    const size_t tb = (size_t)tok * G3;

    const float4 tr = *(const float4*)&tokgi[tb + j];
    const float4 tz = *(const float4*)&tokgi[tb + 1024 + j];
    const float4 tn = *(const float4*)&tokgi[tb + 2048 + j];
    const float4 xr = *(const float4*)&gx0[gb + j];
    const float4 xz = *(const float4*)&gx0[gb + 1024 + j];
    const float4 xn = *(const float4*)&gx0[gb + 2048 + j];
    const float4 hr = *(const float4*)&gh[lb + j];
    const float4 hz = *(const float4*)&gh[lb + 1024 + j];
    const float4 hn = *(const float4*)&gh[lb + 2048 + j];
    const size_t hidx = (size_t)b * DECD + j;
    const half4v ph = *(const half4v*)&hh[hidx];
    const half4v pl = *(const half4v*)&hl[hidx];

    half4v sh, sl;
#pragma unroll
    for (int c = 0; c < 4; ++c) {
        const float hp = join2(ph[c], pl[c]);
        const float r = 1.f / (1.f + expf(-((&tr.x)[c] + (&xr.x)[c] + (&hr.x)[c])));
        const float z = 1.f / (1.f + expf(-((&tz.x)[c] + (&xz.x)[c] + (&hz.x)[c])));
        const float n = tanhf((&tn.x)[c] + (&xn.x)[c] + r * (&hn.x)[c]);
        const float hv = (1.f - z) * n + z * hp;
        f16 a, bb; split2(hv, a, bb); sh[c] = a; sl[c] = bb;
    }
    *(half4v*)&hh[hidx] = sh;
    *(half4v*)&hl[hidx] = sl;
}

// ---------------- fused logits + argmax + CE (fp32 compute, split-h input) ----------------
#define LROWS 16
#define LKC   256

__global__ __launch_bounds__(256, 2)
void logits_kernel(const f16* __restrict__ hh, const f16* __restrict__ hl,
                   const float* __restrict__ Wp, const float* __restrict__ bp,
                   const int* __restrict__ tseq,
                   int t, float* __restrict__ pred, float* __restrict__ accb)
{
    __shared__ float hs[LROWS][LKC];
    const int tid  = threadIdx.x;
    const int lane = tid & 63;
    const int wv   = tid >> 6;
    const int b0   = blockIdx.x * LROWS;
    const bool v2  = (lane < VOCAB - 128);

    float acc0[4], acc1[4], acc2[4];
#pragma unroll
    for (int r = 0; r < 4; ++r) { acc0[r] = 0.f; acc1[r] = 0.f; acc2[r] = 0.f; }

    const int r0 = wv * 4;
    for (int kc = 0; kc < DECD; kc += LKC) {
        __syncthreads();
#pragma unroll
        for (int j = 0; j < 2; ++j) {
            const int f = tid + j * 256;          // 512 groups of 8 cols
            const int row = f >> 5, g = f & 31;
            const size_t src = (size_t)(b0 + row) * DECD + kc + g * 8;
            const half8 vh = *(const half8*)&hh[src];
            const half8 vl = *(const half8*)&hl[src];
            float4 o0, o1;
#pragma unroll
            for (int c = 0; c < 4; ++c) {
                (&o0.x)[c] = join2(vh[c], vl[c]);
                (&o1.x)[c] = join2(vh[c + 4], vl[c + 4]);
            }
            *reinterpret_cast<float4*>(&hs[row][g*8])     = o0;
            *reinterpret_cast<float4*>(&hs[row][g*8 + 4]) = o1;
        }
        __syncthreads();
        for (int k4 = 0; k4 < LKC/4; ++k4) {
            float4 hv[4];
#pragma unroll
            for (int r = 0; r < 4; ++r)
                hv[r] = *reinterpret_cast<const float4*>(&hs[r0+r][k4*4]);
#pragma unroll
            for (int kk = 0; kk < 4; ++kk) {
                const int kg = kc + k4*4 + kk;
                const float w0 = Wp[(size_t)kg*VOCAB + lane];
                const float w1 = Wp[(size_t)kg*VOCAB + lane + 64];
                const float w2 = v2 ? Wp[(size_t)kg*VOCAB + lane + 128] : 0.f;
#pragma unroll
                for (int r = 0; r < 4; ++r) {
                    const float hrk = (&hv[r].x)[kk];
                    acc0[r] = fmaf(hrk, w0, acc0[r]);
                    acc1[r] = fmaf(hrk, w1, acc1[r]);
                    acc2[r] = fmaf(hrk, w2, acc2[r]);
                }
            }
        }
    }

    float wnll = 0.f, wcnt = 0.f;
    for (int r = 0; r < 4; ++r) {
        const int b = b0 + r0 + r;
        const float l0 = acc0[r] + bp[lane];
        const float l1 = acc1[r] + bp[lane + 64];
        const float l2 = v2 ? (acc2[r] + bp[lane + 128]) : 0.f;
        float m = l0; int mi = lane;
        if (l1 > m) { m = l1; mi = lane + 64; }
        if (v2 && l2 > m) { m = l2; mi = lane + 128; }
#pragma unroll
        for (int off = 32; off >= 1; off >>= 1) {
            const float om = __shfl_xor(m, off);
            const int   oi = __shfl_xor(mi, off);
            if (om > m || (om == m && oi < mi)) { m = om; mi = oi; }
        }
        const int tgt = tseq[(size_t)b * TLEN + t];
        float se = expf(l0 - m) + expf(l1 - m) + (v2 ? expf(l2 - m) : 0.f);
        const int ts = tgt >> 6, tl_lane = tgt & 63;
        float tl = (lane == tl_lane) ? ((ts == 0) ? l0 : (ts == 1) ? l1 : l2) : 0.f;
#pragma unroll
        for (int off = 32; off >= 1; off >>= 1) {
            se += __shfl_xor(se, off);
            tl += __shfl_xor(tl, off);
        }
        if (lane == 0) {
            if (mi < OUTC) pred[(size_t)b * OUTC + mi] = 1.0f;
            if (tgt != IGN_TOK) { wnll += (m + logf(se)) - tl; wcnt += 1.f; }
        }
    }
    if (lane == 0) {
        atomicAdd(&accb[0], wnll);
        atomicAdd(&accb[1], wcnt);
    }
}

__global__ void finalize_loss(const float* __restrict__ accb, float* __restrict__ out)
{
    out[0] = accb[0] / fmaxf(accb[1], 1.f);
}

extern "C" void kernel_launch(void* const* d_in, const int* in_sizes, int n_in,
                              void* d_out, int out_size, void* d_ws, size_t ws_size,
                              hipStream_t stream)
{
    const float* s    = (const float*)d_in[0];
    const int*   aseq = (const int*)  d_in[1];
    const float* W1   = (const float*)d_in[2];
    const float* b1   = (const float*)d_in[3];
    const float* W2   = (const float*)d_in[4];
    const float* b2   = (const float*)d_in[5];
    const float* emb  = (const float*)d_in[6];
    const float* Wih  = (const float*)d_in[7];
    const float* Whh  = (const float*)d_in[8];
    const float* bih  = (const float*)d_in[9];
    const float* bhh  = (const float*)d_in[10];
    const float* Wp   = (const float*)d_in[11];
    const float* bp   = (const float*)d_in[12];
    float* outp = (float*)d_out;
    char* W = (char*)d_ws;

    // ---- arena (bytes) — total ~199.3 MB, fits the >=237 MB proven workspace ----
    const size_t o_gx0 = 0;                                  // [8192,3072] f32 = 100.66 MB
    const size_t o_hh  = o_gx0 + (size_t)BATCH * G3 * 4;     // [8192,1024] f16
    const size_t o_hl  = o_hh  + (size_t)BATCH * DECD * 2;
    const size_t o_tg  = o_hl  + (size_t)BATCH * DECD * 2;   // [169,3072] f32
    const size_t o_whh = o_tg  + (size_t)VOCAB * G3 * 4;     // Whh^T split
    const size_t o_whl = o_whh + (size_t)DECD * G3 * 2;
    const size_t o_acc = o_whl + (size_t)DECD * G3 * 2;
    const size_t o_gh  = o_acc + 256;                        // [4096,3072] f32 chunk
    const size_t need  = o_gh + (size_t)MCHUNK * G3 * 4;
    if (ws_size < need) return;

    float* gx0  = (float*)(W + o_gx0);
    f16*   hh   = (f16*)(W + o_hh);
    f16*   hl   = (f16*)(W + o_hl);
    float* tg   = (float*)(W + o_tg);
    f16*   whh  = (f16*)(W + o_whh);
    f16*   whl  = (f16*)(W + o_whl);
    float* accb = (float*)(W + o_acc);
    float* gh   = (float*)(W + o_gh);

    // setup transients aliased into dead regions:
    f16* h1h = (f16*)(W + o_gx0);                                  // [8192,2048] in gx0 region
    f16* h1l = (f16*)(W + o_gx0 + (size_t)BATCH * HDIM * 2);
    f16* sh  = (f16*)(W + o_gh);                                   // [8192,1024] in gh region
    f16* sl  = (f16*)(W + o_gh + (size_t)BATCH * SDIM * 2);
    f16* w1h = (f16*)(W + o_gh + (size_t)BATCH * SDIM * 4);        // after sh/sl (33.55 MB)
    f16* w1l = (f16*)(W + o_gh + (size_t)BATCH * SDIM * 4 + (size_t)SDIM * HDIM * 2);
    f16* w2h = (f16*)(W + o_gh);                                   // over dead sh after gemm1
    f16* w2l = (f16*)(W + o_gh + (size_t)HDIM * DECD * 2);
    f16* wih = (f16*)(W + o_gh + (size_t)HDIM * DECD * 4);         // 8.39 MB in
    f16* wil = (f16*)(W + o_gh + (size_t)HDIM * DECD * 4 + (size_t)DECD * G3 * 2);

    hipMemsetAsync(d_out, 0, (size_t)out_size * sizeof(float), stream);
    hipMemsetAsync(accb, 0, 2 * sizeof(float), stream);

    // ---- setup: splits, transposes, encoder, gx0, token table ----
    split_act<<<dim3(BATCH * SDIM / 4 / 256), 256, 0, stream>>>(s, sh, sl);
    transpose_split<<<dim3(HDIM/32, SDIM/32), 256, 0, stream>>>(W1, w1h, w1l, SDIM, HDIM);
    tok_gi<<<dim3(G3/256, VOCAB), 256, 0, stream>>>(emb, Wih, tg);

    // h1 = relu(s@W1+b1): split only, into gx0 region
    gemm16<2><<<dim3((BATCH/128)*(HDIM/128)), 256, 0, stream>>>(
        sh, sl, w1h, w1l, b1, nullptr, h1h, h1l, BATCH, HDIM, SDIM, 1);

    transpose_split<<<dim3(DECD/32, HDIM/32), 256, 0, stream>>>(W2, w2h, w2l, HDIM, DECD);
    // h0 = h1@W2+b2: split only (h lives as hh/hl)
    gemm16<2><<<dim3((BATCH/128)*(DECD/128)), 256, 0, stream>>>(
        h1h, h1l, w2h, w2l, b2, nullptr, hh, hl, BATCH, DECD, HDIM, 0);

    transpose_split<<<dim3(G3/32, DECD/32), 256, 0, stream>>>(Wih + (size_t)EMBD * G3, wih, wil, DECD, G3);
    // gx0 = h0@Wih[256:]+bih (f32, persistent; overwrites dead h1)
    gemm16<1><<<dim3((BATCH/128)*(G3/128)), 256, 0, stream>>>(
        hh, hl, wih, wil, bih, gx0, nullptr, nullptr, BATCH, G3, DECD, 0);

    transpose_split<<<dim3(G3/32, DECD/32), 256, 0, stream>>>(Whh, whh, whl, DECD, G3);

    // ---- decoder loop: 2 half-batch chunks share one gh buffer (stream-serialized) ----
    for (int t = 0; t < TLEN; ++t) {
        for (int c = 0; c < 2; ++c) {
            const int b0g = c * MCHUNK;
            gemm16<1><<<dim3((MCHUNK/128)*(G3/128)), 256, 0, stream>>>(
                hh + (size_t)b0g * DECD, hl + (size_t)b0g * DECD, whh, whl,
                bhh, gh, nullptr, nullptr, MCHUNK, G3, DECD, 0);
            gru_gates<<<dim3(MCHUNK * DECD / 4 / 256), 256, 0, stream>>>(
                gh, gx0, tg, aseq, t, b0g, hh, hl);
        }
        logits_kernel<<<dim3(BATCH / LROWS), 256, 0, stream>>>(
            hh, hl, Wp, bp, aseq, t, outp + 1, accb);
    }
    finalize_loss<<<1, 1, 0, stream>>>(accb, outp);
}

// Round 4
// 7959.092 us; speedup vs baseline: 2.2056x; 1.0332x over previous
//
#include <hip/hip_runtime.h>
#include <math.h>

typedef _Float16 f16;
typedef _Float16 half8 __attribute__((ext_vector_type(8)));
typedef _Float16 half4v __attribute__((ext_vector_type(4)));
typedef float f32x4 __attribute__((ext_vector_type(4)));

#define BATCH 8192
#define SDIM  1024
#define HDIM  2048
#define DECD  1024
#define EMBD  256
#define G3    3072
#define VOCAB 169
#define VPAD  176
#define NFRAG 11
#define TLEN  20
#define SOS_TOK 166
#define IGN_TOK 168
#define OUTC  166
#define MCHUNK 4096

#define GLOAD16(gp, lp) __builtin_amdgcn_global_load_lds( \
    (const __attribute__((address_space(1))) unsigned int*)(gp), \
    (__attribute__((address_space(3))) unsigned int*)(lp), 16, 0, 0)

// fp16x2 split: a ~= hi + lo/2048, avoids fp16-subnormal hi for tiny a
__device__ __forceinline__ void split2(float a, f16& h, f16& l)
{
    float hi = (fabsf(a) >= 6.103515625e-05f) ? (float)(f16)a : 0.0f;
    h = (f16)hi;
    l = (f16)((a - hi) * 2048.0f);
}

__device__ __forceinline__ float join2(f16 h, f16 l)
{
    return (float)h + (float)l * 4.8828125e-4f;
}

// LDS tile layout (A and B identical): logical (r in [0,128), k in [0,32)).
// 128B "lines" hold row pairs; 16B slots XOR-swizzled by line&7 so that
// ds_read_b128 fragment reads are ~2-way (free) bank accesses.
__device__ __forceinline__ int swz(int r, int k0)   // halfword offset
{
    const int line = r >> 1;
    const int s = (((r & 1) << 2) | (k0 >> 3)) ^ (line & 7);
    return line * 64 + s * 8;
}

// ============ fp16x2 3-pass MFMA GEMM: C = op(A[M,K] @ Bt[N,K]^T + bias) ============
// MODE bit0: write fp32 C; bit1: write split (Ch, Cl)
template<int MODE>
__global__ __launch_bounds__(256, 2)
void gemm16(const f16* __restrict__ Ah, const f16* __restrict__ Al,
            const f16* __restrict__ Bh, const f16* __restrict__ Bl,
            const float* __restrict__ bias, float* __restrict__ C,
            f16* __restrict__ Ch, f16* __restrict__ Cl,
            int M, int N, int K, int relu)
{
    __shared__ __align__(16) f16 lds[4][4096];   // Ahi, Alo, Bhi, Blo (8KB each)

    const int nx = N >> 7;
    const int cpx = gridDim.x >> 3;              // grids are %8==0
    int wg = blockIdx.x;
    wg = (wg & 7) * cpx + (wg >> 3);             // XCD-aware swizzle
    const int m0 = (wg / nx) << 7;
    const int n0 = (wg % nx) << 7;

    const int tid = threadIdx.x;
    const int w = tid >> 6;
    const int lane = tid & 63;
    const int wr = w >> 1, wc = w & 1;

    // staging: per-lane global source offset implementing the LDS swizzle
    const int qq = (lane & 7) ^ (lane >> 3);
    const int row_off = ((lane >> 3) << 1) | (qq >> 2);
    const int k_off = (qq & 3) << 3;
    const f16* sb = (w == 0) ? Ah + (size_t)m0 * K
                  : (w == 1) ? Al + (size_t)m0 * K
                  : (w == 2) ? Bh + (size_t)n0 * K
                             : Bl + (size_t)n0 * K;
    sb += (size_t)row_off * K + k_off;
    f16* lb = &lds[w][0];

    // fragment ds_read offsets (constant across K-steps)
    int offA[4], offB[4];
    {
        const int fr = lane & 15, k0 = (lane >> 4) << 3;
#pragma unroll
        for (int t = 0; t < 4; ++t) {
            offA[t] = swz(wr * 64 + t * 16 + fr, k0);
            offB[t] = swz(wc * 64 + t * 16 + fr, k0);
        }
    }

    f32x4 acch[4][4], accl[4][4];
#pragma unroll
    for (int i = 0; i < 4; ++i)
#pragma unroll
        for (int j = 0; j < 4; ++j) { acch[i][j] = (f32x4)0.0f; accl[i][j] = (f32x4)0.0f; }

    const int nkt = K >> 5;
    const size_t K16 = (size_t)K * 16;
    for (int kt = 0; kt < nkt; ++kt) {
        const f16* s = sb + kt * 32;
#pragma unroll
        for (int i = 0; i < 8; ++i)
            GLOAD16(s + (size_t)i * K16, lb + i * 512);
        __syncthreads();

        half8 fah[4], fbh[4], fal[4], fbl[4];
#pragma unroll
        for (int t = 0; t < 4; ++t) {
            fah[t] = *(const half8*)&lds[0][offA[t]];
            fal[t] = *(const half8*)&lds[1][offA[t]];
            fbh[t] = *(const half8*)&lds[2][offB[t]];
            fbl[t] = *(const half8*)&lds[3][offB[t]];
        }
#pragma unroll
        for (int i = 0; i < 4; ++i)
#pragma unroll
            for (int j = 0; j < 4; ++j) {
                acch[i][j] = __builtin_amdgcn_mfma_f32_16x16x32_f16(fah[i], fbh[j], acch[i][j], 0, 0, 0);
                accl[i][j] = __builtin_amdgcn_mfma_f32_16x16x32_f16(fal[i], fbh[j], accl[i][j], 0, 0, 0);
                accl[i][j] = __builtin_amdgcn_mfma_f32_16x16x32_f16(fah[i], fbl[j], accl[i][j], 0, 0, 0);
            }
        __syncthreads();
    }

    // epilogue: C/D layout col=lane&15, row=(lane>>4)*4+reg
    const float inv2048 = 4.8828125e-4f;
    const int fr = lane & 15;
    const int fq = lane >> 4;
#pragma unroll
    for (int j = 0; j < 4; ++j) {
        const int col = n0 + wc * 64 + j * 16 + fr;
        const float bc = bias[col];
#pragma unroll
        for (int i = 0; i < 4; ++i) {
            const int row0 = m0 + wr * 64 + i * 16 + fq * 4;
            const f32x4 vh = acch[i][j], vl = accl[i][j];
#pragma unroll
            for (int r = 0; r < 4; ++r) {
                float v = vh[r] + vl[r] * inv2048 + bc;
                if (relu) v = fmaxf(v, 0.0f);
                const size_t o = (size_t)(row0 + r) * N + col;
                if constexpr (MODE & 1) C[o] = v;
                if constexpr (MODE & 2) { f16 hh, hl; split2(v, hh, hl); Ch[o] = hh; Cl[o] = hl; }
            }
        }
    }
}

// ============ weight transpose + split: W[K][N] -> Wt_hi/lo [N][K] ============
__global__ __launch_bounds__(256)
void transpose_split(const float* __restrict__ Wm, f16* __restrict__ th, f16* __restrict__ tl,
                     int K, int N)
{
    __shared__ float tile[32][33];
    const int n0 = blockIdx.x << 5, k0 = blockIdx.y << 5;
    const int tx = threadIdx.x & 31, ty = threadIdx.x >> 5;
#pragma unroll
    for (int j = 0; j < 32; j += 8)
        tile[ty + j][tx] = Wm[(size_t)(k0 + ty + j) * N + n0 + tx];
    __syncthreads();
#pragma unroll
    for (int j = 0; j < 32; j += 8) {
        const float a = tile[tx][ty + j];
        f16 hh, hl; split2(a, hh, hl);
        const size_t o = (size_t)(n0 + ty + j) * K + k0 + tx;
        th[o] = hh; tl[o] = hl;
    }
}

// ============ Wp transpose+split with padding: Wp[1024][169] -> wph/wpl[176][1024] ============
__global__ __launch_bounds__(256)
void wp_split(const float* __restrict__ Wp, f16* __restrict__ wph, f16* __restrict__ wpl)
{
    const int k = blockIdx.x * 256 + threadIdx.x;   // 0..1023
    const int n = blockIdx.y;                        // 0..175
    const float a = (n < VOCAB) ? Wp[(size_t)k * VOCAB + n] : 0.0f;
    f16 h, l; split2(a, h, l);
    wph[(size_t)n * DECD + k] = h;
    wpl[(size_t)n * DECD + k] = l;
}

// ============ activation split (s input) ============
__global__ __launch_bounds__(256)
void split_act(const float* __restrict__ x, f16* __restrict__ xh, f16* __restrict__ xl)
{
    const int i = blockIdx.x * 256 + threadIdx.x;
    const float4 v = ((const float4*)x)[i];
    half4v hh, hl;
#pragma unroll
    for (int c = 0; c < 4; ++c) { f16 a, b; split2((&v.x)[c], a, b); hh[c] = a; hl[c] = b; }
    ((half4v*)xh)[i] = hh;
    ((half4v*)xl)[i] = hl;
}

// ---------------- tokgi[v] = emb[v] @ Wih[0:256, :]  ([169, 3072]) ----------------
__global__ __launch_bounds__(256)
void tok_gi(const float* __restrict__ emb, const float* __restrict__ Wih,
            float* __restrict__ tg)
{
    __shared__ float es[EMBD];
    const int v = blockIdx.y;
    const int n = blockIdx.x * 256 + threadIdx.x;
    es[threadIdx.x] = emb[(size_t)v * EMBD + threadIdx.x];
    __syncthreads();
    float s = 0.f;
#pragma unroll 8
    for (int k = 0; k < EMBD; ++k)
        s = fmaf(es[k], Wih[(size_t)k * G3 + n], s);
    tg[(size_t)v * G3 + n] = s;
}

// ---------------- GRU gates: h(split) updated in place; gh is chunk-local ----------------
__global__ __launch_bounds__(256)
void gru_gates(const float* __restrict__ gh, const float* __restrict__ gx0,
               const float* __restrict__ tokgi, const int* __restrict__ tseq,
               int t, int b0g, f16* __restrict__ hh, f16* __restrict__ hl)
{
    const int i4 = blockIdx.x * 256 + threadIdx.x;
    const int bl = i4 >> 8;          // chunk-local batch row
    const int b  = b0g + bl;         // global batch row
    const int j  = (i4 & 255) << 2;
    const int tok = (t == 0) ? SOS_TOK : tseq[(size_t)b * TLEN + (t - 1)];
    const size_t gb = (size_t)b * G3;
    const size_t lb = (size_t)bl * G3;
    const size_t tb = (size_t)tok * G3;

    const float4 tr = *(const float4*)&tokgi[tb + j];
    const float4 tz = *(const float4*)&tokgi[tb + 1024 + j];
    const float4 tn = *(const float4*)&tokgi[tb + 2048 + j];
    const float4 xr = *(const float4*)&gx0[gb + j];
    const float4 xz = *(const float4*)&gx0[gb + 1024 + j];
    const float4 xn = *(const float4*)&gx0[gb + 2048 + j];
    const float4 hr = *(const float4*)&gh[lb + j];
    const float4 hz = *(const float4*)&gh[lb + 1024 + j];
    const float4 hn = *(const float4*)&gh[lb + 2048 + j];
    const size_t hidx = (size_t)b * DECD + j;
    const half4v ph = *(const half4v*)&hh[hidx];
    const half4v pl = *(const half4v*)&hl[hidx];

    half4v sh, sl;
#pragma unroll
    for (int c = 0; c < 4; ++c) {
        const float hp = join2(ph[c], pl[c]);
        const float r = 1.f / (1.f + expf(-((&tr.x)[c] + (&xr.x)[c] + (&hr.x)[c])));
        const float z = 1.f / (1.f + expf(-((&tz.x)[c] + (&xz.x)[c] + (&hz.x)[c])));
        const float n = tanhf((&tn.x)[c] + (&xn.x)[c] + r * (&hn.x)[c]);
        const float hv = (1.f - z) * n + z * hp;
        f16 a, bb; split2(hv, a, bb); sh[c] = a; sl[c] = bb;
    }
    *(half4v*)&hh[hidx] = sh;
    *(half4v*)&hl[hidx] = sl;
}

// ---------------- MFMA logits + argmax + CE ----------------
// 1 wave / 16 batch rows. 11 n-frags of 16 cols (VOCAB padded to 176).
// A/B fragments loaded directly from global (B is L2-resident, 720 KB).
__global__ __launch_bounds__(64)
void logits_mfma(const f16* __restrict__ hh, const f16* __restrict__ hl,
                 const f16* __restrict__ wph, const f16* __restrict__ wpl,
                 const float* __restrict__ bp, const int* __restrict__ tseq,
                 int t, float* __restrict__ pred, float* __restrict__ accb)
{
    const int lane = threadIdx.x;
    const int b0 = blockIdx.x << 4;
    const int fr = lane & 15, kq = lane >> 4;

    const f16* pa_h = hh + (size_t)(b0 + fr) * DECD + kq * 8;
    const f16* pa_l = hl + (size_t)(b0 + fr) * DECD + kq * 8;
    const f16* pb_h = wph + (size_t)fr * DECD + kq * 8;
    const f16* pb_l = wpl + (size_t)fr * DECD + kq * 8;

    f32x4 acch[NFRAG], accl[NFRAG];
#pragma unroll
    for (int f = 0; f < NFRAG; ++f) { acch[f] = (f32x4)0.0f; accl[f] = (f32x4)0.0f; }

#pragma unroll 2
    for (int kt = 0; kt < DECD / 32; ++kt) {
        const int ko = kt * 32;
        const half8 a_h = *(const half8*)(pa_h + ko);
        const half8 a_l = *(const half8*)(pa_l + ko);
#pragma unroll
        for (int f = 0; f < NFRAG; ++f) {
            const half8 b_h = *(const half8*)(pb_h + (size_t)f * 16 * DECD + ko);
            const half8 b_l = *(const half8*)(pb_l + (size_t)f * 16 * DECD + ko);
            acch[f] = __builtin_amdgcn_mfma_f32_16x16x32_f16(a_h, b_h, acch[f], 0, 0, 0);
            accl[f] = __builtin_amdgcn_mfma_f32_16x16x32_f16(a_l, b_h, accl[f], 0, 0, 0);
            accl[f] = __builtin_amdgcn_mfma_f32_16x16x32_f16(a_h, b_l, accl[f], 0, 0, 0);
        }
    }

    // epilogue: C/D layout col=lane&15, row=kq*4+reg (16 rows per wave)
    float wnll = 0.f, wcnt = 0.f;
#pragma unroll
    for (int r = 0; r < 4; ++r) {
        const int b = b0 + kq * 4 + r;
        float v[NFRAG];
        float m = -3.0e38f; int mi = 0;
#pragma unroll
        for (int f = 0; f < NFRAG; ++f) {
            const int col = f * 16 + fr;
            const float bb = (col < VOCAB) ? bp[col] : -1.0e30f;
            v[f] = acch[f][r] + accl[f][r] * 4.8828125e-4f + bb;
            if (v[f] > m) { m = v[f]; mi = col; }
        }
        // reduce over the 16 lanes of this quarter-group (xor masks 1..8)
#pragma unroll
        for (int off = 8; off >= 1; off >>= 1) {
            const float om = __shfl_xor(m, off);
            const int   oi = __shfl_xor(mi, off);
            if (om > m || (om == m && oi < mi)) { m = om; mi = oi; }
        }
        const int tgt = tseq[(size_t)b * TLEN + t];
        float se = 0.f, tl = 0.f;
#pragma unroll
        for (int f = 0; f < NFRAG; ++f) {
            se += expf(v[f] - m);                       // pads: exp(-1e30-m) -> 0
            if ((tgt >> 4) == f && (tgt & 15) == fr) tl = v[f];
        }
#pragma unroll
        for (int off = 8; off >= 1; off >>= 1) {
            se += __shfl_xor(se, off);
            tl += __shfl_xor(tl, off);
        }
        if (fr == 0) {
            if (mi < OUTC) pred[(size_t)b * OUTC + mi] = 1.0f;
            if (tgt != IGN_TOK) { wnll += m + logf(se) - tl; wcnt += 1.f; }
        }
    }
    wnll += __shfl_xor(wnll, 16); wnll += __shfl_xor(wnll, 32);
    wcnt += __shfl_xor(wcnt, 16); wcnt += __shfl_xor(wcnt, 32);
    if (lane == 0) {
        atomicAdd(&accb[0], wnll);
        atomicAdd(&accb[1], wcnt);
    }
}

__global__ void finalize_loss(const float* __restrict__ accb, float* __restrict__ out)
{
    out[0] = accb[0] / fmaxf(accb[1], 1.f);
}

extern "C" void kernel_launch(void* const* d_in, const int* in_sizes, int n_in,
                              void* d_out, int out_size, void* d_ws, size_t ws_size,
                              hipStream_t stream)
{
    const float* s    = (const float*)d_in[0];
    const int*   aseq = (const int*)  d_in[1];
    const float* W1   = (const float*)d_in[2];
    const float* b1   = (const float*)d_in[3];
    const float* W2   = (const float*)d_in[4];
    const float* b2   = (const float*)d_in[5];
    const float* emb  = (const float*)d_in[6];
    const float* Wih  = (const float*)d_in[7];
    const float* Whh  = (const float*)d_in[8];
    const float* bih  = (const float*)d_in[9];
    const float* bhh  = (const float*)d_in[10];
    const float* Wp   = (const float*)d_in[11];
    const float* bp   = (const float*)d_in[12];
    float* outp = (float*)d_out;
    char* W = (char*)d_ws;

    // ---- arena (bytes) — ~200 MB, fits the >=237 MB proven workspace ----
    const size_t o_gx0 = 0;                                  // [8192,3072] f32 = 100.66 MB
    const size_t o_hh  = o_gx0 + (size_t)BATCH * G3 * 4;     // [8192,1024] f16
    const size_t o_hl  = o_hh  + (size_t)BATCH * DECD * 2;
    const size_t o_tg  = o_hl  + (size_t)BATCH * DECD * 2;   // [169,3072] f32
    const size_t o_whh = o_tg  + (size_t)VOCAB * G3 * 4;     // Whh^T split
    const size_t o_whl = o_whh + (size_t)DECD * G3 * 2;
    const size_t o_wph = o_whl + (size_t)DECD * G3 * 2;      // Wp^T split, padded to 176
    const size_t o_wpl = o_wph + (size_t)VPAD * DECD * 2;
    const size_t o_acc = o_wpl + (size_t)VPAD * DECD * 2;
    const size_t o_gh  = o_acc + 256;                        // [4096,3072] f32 chunk
    const size_t need  = o_gh + (size_t)MCHUNK * G3 * 4;
    if (ws_size < need) return;

    float* gx0  = (float*)(W + o_gx0);
    f16*   hh   = (f16*)(W + o_hh);
    f16*   hl   = (f16*)(W + o_hl);
    float* tg   = (float*)(W + o_tg);
    f16*   whh  = (f16*)(W + o_whh);
    f16*   whl  = (f16*)(W + o_whl);
    f16*   wph  = (f16*)(W + o_wph);
    f16*   wpl  = (f16*)(W + o_wpl);
    float* accb = (float*)(W + o_acc);
    float* gh   = (float*)(W + o_gh);

    // setup transients aliased into dead regions:
    f16* h1h = (f16*)(W + o_gx0);                                  // [8192,2048] in gx0 region
    f16* h1l = (f16*)(W + o_gx0 + (size_t)BATCH * HDIM * 2);
    f16* sh  = (f16*)(W + o_gh);                                   // [8192,1024] in gh region
    f16* sl  = (f16*)(W + o_gh + (size_t)BATCH * SDIM * 2);
    f16* w1h = (f16*)(W + o_gh + (size_t)BATCH * SDIM * 4);        // after sh/sl
    f16* w1l = (f16*)(W + o_gh + (size_t)BATCH * SDIM * 4 + (size_t)SDIM * HDIM * 2);
    f16* w2h = (f16*)(W + o_gh);                                   // over dead sh after gemm1
    f16* w2l = (f16*)(W + o_gh + (size_t)HDIM * DECD * 2);
    f16* wih = (f16*)(W + o_gh + (size_t)HDIM * DECD * 4);
    f16* wil = (f16*)(W + o_gh + (size_t)HDIM * DECD * 4 + (size_t)DECD * G3 * 2);

    hipMemsetAsync(d_out, 0, (size_t)out_size * sizeof(float), stream);
    hipMemsetAsync(accb, 0, 2 * sizeof(float), stream);

    // ---- setup: splits, transposes, encoder, gx0, token table ----
    split_act<<<dim3(BATCH * SDIM / 4 / 256), 256, 0, stream>>>(s, sh, sl);
    transpose_split<<<dim3(HDIM/32, SDIM/32), 256, 0, stream>>>(W1, w1h, w1l, SDIM, HDIM);
    tok_gi<<<dim3(G3/256, VOCAB), 256, 0, stream>>>(emb, Wih, tg);
    wp_split<<<dim3(DECD/256, VPAD), 256, 0, stream>>>(Wp, wph, wpl);

    // h1 = relu(s@W1+b1): split only, into gx0 region
    gemm16<2><<<dim3((BATCH/128)*(HDIM/128)), 256, 0, stream>>>(
        sh, sl, w1h, w1l, b1, nullptr, h1h, h1l, BATCH, HDIM, SDIM, 1);

    transpose_split<<<dim3(DECD/32, HDIM/32), 256, 0, stream>>>(W2, w2h, w2l, HDIM, DECD);
    // h0 = h1@W2+b2: split only (h lives as hh/hl)
    gemm16<2><<<dim3((BATCH/128)*(DECD/128)), 256, 0, stream>>>(
        h1h, h1l, w2h, w2l, b2, nullptr, hh, hl, BATCH, DECD, HDIM, 0);

    transpose_split<<<dim3(G3/32, DECD/32), 256, 0, stream>>>(Wih + (size_t)EMBD * G3, wih, wil, DECD, G3);
    // gx0 = h0@Wih[256:]+bih (f32, persistent; overwrites dead h1)
    gemm16<1><<<dim3((BATCH/128)*(G3/128)), 256, 0, stream>>>(
        hh, hl, wih, wil, bih, gx0, nullptr, nullptr, BATCH, G3, DECD, 0);

    transpose_split<<<dim3(G3/32, DECD/32), 256, 0, stream>>>(Whh, whh, whl, DECD, G3);

    // ---- decoder loop: 2 half-batch chunks share one gh buffer (stream-serialized) ----
    for (int t = 0; t < TLEN; ++t) {
        for (int c = 0; c < 2; ++c) {
            const int b0g = c * MCHUNK;
            gemm16<1><<<dim3((MCHUNK/128)*(G3/128)), 256, 0, stream>>>(
                hh + (size_t)b0g * DECD, hl + (size_t)b0g * DECD, whh, whl,
                bhh, gh, nullptr, nullptr, MCHUNK, G3, DECD, 0);
            gru_gates<<<dim3(MCHUNK * DECD / 4 / 256), 256, 0, stream>>>(
                gh, gx0, tg, aseq, t, b0g, hh, hl);
        }
        logits_mfma<<<dim3(BATCH / 16), 64, 0, stream>>>(
            hh, hl, wph, wpl, bp, aseq, t, outp + 1, accb);
    }
    finalize_loss<<<1, 1, 0, stream>>>(accb, outp);
}

// Round 5
// 7114.723 us; speedup vs baseline: 2.4673x; 1.1187x over previous
//
#include <hip/hip_runtime.h>
#include <math.h>

typedef _Float16 f16;
typedef _Float16 half8 __attribute__((ext_vector_type(8)));
typedef _Float16 half4v __attribute__((ext_vector_type(4)));
typedef float f32x4 __attribute__((ext_vector_type(4)));

#define BATCH 8192
#define SDIM  1024
#define HDIM  2048
#define DECD  1024
#define EMBD  256
#define G3    3072
#define VOCAB 169
#define VPAD  176
#define NFRAG 11
#define TLEN  20
#define SOS_TOK 166
#define IGN_TOK 168
#define OUTC  166

#define GLOAD16(gp, lp) __builtin_amdgcn_global_load_lds( \
    (const __attribute__((address_space(1))) unsigned int*)(gp), \
    (__attribute__((address_space(3))) unsigned int*)(lp), 16, 0, 0)

// fp16x2 split: a ~= hi + lo/2048, avoids fp16-subnormal hi for tiny a
__device__ __forceinline__ void split2(float a, f16& h, f16& l)
{
    float hi = (fabsf(a) >= 6.103515625e-05f) ? (float)(f16)a : 0.0f;
    h = (f16)hi;
    l = (f16)((a - hi) * 2048.0f);
}

__device__ __forceinline__ float join2(f16 h, f16 l)
{
    return (float)h + (float)l * 4.8828125e-4f;
}

// LDS tile swizzle: rows paired into 128B lines, 16B slots XORed by line&7
__device__ __forceinline__ int swz(int r, int k0)   // halfword offset
{
    const int line = r >> 1;
    const int s = (((r & 1) << 2) | (k0 >> 3)) ^ (line & 7);
    return line * 64 + s * 8;
}

// ============ fp16x2 3-pass MFMA GEMM: C = op(A[M,K] @ Bt[N,K]^T + bias) ============
// MODE bit0: write fp32 C; bit1: write split (Ch, Cl)
template<int MODE>
__global__ __launch_bounds__(256, 2)
void gemm16(const f16* __restrict__ Ah, const f16* __restrict__ Al,
            const f16* __restrict__ Bh, const f16* __restrict__ Bl,
            const float* __restrict__ bias, float* __restrict__ C,
            f16* __restrict__ Ch, f16* __restrict__ Cl,
            int M, int N, int K, int relu)
{
    __shared__ __align__(16) f16 lds[4][4096];   // Ahi, Alo, Bhi, Blo (8KB each)

    const int nx = N >> 7;
    const int cpx = gridDim.x >> 3;              // grids are %8==0
    int wg = blockIdx.x;
    wg = (wg & 7) * cpx + (wg >> 3);             // XCD-aware swizzle
    const int m0 = (wg / nx) << 7;
    const int n0 = (wg % nx) << 7;

    const int tid = threadIdx.x;
    const int w = tid >> 6;
    const int lane = tid & 63;
    const int wr = w >> 1, wc = w & 1;

    const int qq = (lane & 7) ^ (lane >> 3);
    const int row_off = ((lane >> 3) << 1) | (qq >> 2);
    const int k_off = (qq & 3) << 3;
    const f16* sb = (w == 0) ? Ah + (size_t)m0 * K
                  : (w == 1) ? Al + (size_t)m0 * K
                  : (w == 2) ? Bh + (size_t)n0 * K
                             : Bl + (size_t)n0 * K;
    sb += (size_t)row_off * K + k_off;
    f16* lb = &lds[w][0];

    int offA[4], offB[4];
    {
        const int fr = lane & 15, k0 = (lane >> 4) << 3;
#pragma unroll
        for (int t = 0; t < 4; ++t) {
            offA[t] = swz(wr * 64 + t * 16 + fr, k0);
            offB[t] = swz(wc * 64 + t * 16 + fr, k0);
        }
    }

    f32x4 acch[4][4], accl[4][4];
#pragma unroll
    for (int i = 0; i < 4; ++i)
#pragma unroll
        for (int j = 0; j < 4; ++j) { acch[i][j] = (f32x4)0.0f; accl[i][j] = (f32x4)0.0f; }

    const int nkt = K >> 5;
    const size_t K16 = (size_t)K * 16;
    for (int kt = 0; kt < nkt; ++kt) {
        const f16* s = sb + kt * 32;
#pragma unroll
        for (int i = 0; i < 8; ++i)
            GLOAD16(s + (size_t)i * K16, lb + i * 512);
        __syncthreads();

        half8 fah[4], fbh[4], fal[4], fbl[4];
#pragma unroll
        for (int t = 0; t < 4; ++t) {
            fah[t] = *(const half8*)&lds[0][offA[t]];
            fal[t] = *(const half8*)&lds[1][offA[t]];
            fbh[t] = *(const half8*)&lds[2][offB[t]];
            fbl[t] = *(const half8*)&lds[3][offB[t]];
        }
#pragma unroll
        for (int i = 0; i < 4; ++i)
#pragma unroll
            for (int j = 0; j < 4; ++j) {
                acch[i][j] = __builtin_amdgcn_mfma_f32_16x16x32_f16(fah[i], fbh[j], acch[i][j], 0, 0, 0);
                accl[i][j] = __builtin_amdgcn_mfma_f32_16x16x32_f16(fal[i], fbh[j], accl[i][j], 0, 0, 0);
                accl[i][j] = __builtin_amdgcn_mfma_f32_16x16x32_f16(fah[i], fbl[j], accl[i][j], 0, 0, 0);
            }
        __syncthreads();
    }

    const float inv2048 = 4.8828125e-4f;
    const int fr = lane & 15;
    const int fq = lane >> 4;
#pragma unroll
    for (int j = 0; j < 4; ++j) {
        const int col = n0 + wc * 64 + j * 16 + fr;
        const float bc = bias[col];
#pragma unroll
        for (int i = 0; i < 4; ++i) {
            const int row0 = m0 + wr * 64 + i * 16 + fq * 4;
            const f32x4 vh = acch[i][j], vl = accl[i][j];
#pragma unroll
            for (int r = 0; r < 4; ++r) {
                float v = vh[r] + vl[r] * inv2048 + bc;
                if (relu) v = fmaxf(v, 0.0f);
                const size_t o = (size_t)(row0 + r) * N + col;
                if constexpr (MODE & 1) C[o] = v;
                if constexpr (MODE & 2) { f16 hh, hl; split2(v, hh, hl); Ch[o] = hh; Cl[o] = hl; }
            }
        }
    }
}

// ============ fused decoder step: gh = h@Whh^T (3 gates) + GRU gate math ============
// block: 128 batch rows x 64 hidden cols; 4 waves, wave tile 64x32.
// Double-buffered LDS staging (2-phase). Writes h_{t+1} split to a separate buffer.
#define STAGE(SET, KT) do {                                                        \
    const int ko_ = (KT) * 32 + k_off;                                             \
    if (w == 0) {                                                                  \
        const f16* sp = hch + (size_t)(m0 + row_off) * DECD + ko_;                 \
        _Pragma("unroll") for (int i_ = 0; i_ < 8; ++i_)                           \
            GLOAD16(sp + (size_t)i_ * (16 * DECD), &lds[SET][i_ * 512]);           \
    } else if (w == 1) {                                                           \
        const f16* sp = hcl + (size_t)(m0 + row_off) * DECD + ko_;                 \
        _Pragma("unroll") for (int i_ = 0; i_ < 8; ++i_)                           \
            GLOAD16(sp + (size_t)i_ * (16 * DECD), &lds[SET][4096 + i_ * 512]);    \
    } else if (w == 2) {                                                           \
        _Pragma("unroll") for (int g_ = 0; g_ < 3; ++g_) {                         \
            const f16* sp = whh + (size_t)(g_ * DECD + n0 + row_off) * DECD + ko_; \
            _Pragma("unroll") for (int i_ = 0; i_ < 4; ++i_)                       \
                GLOAD16(sp + (size_t)i_ * (16 * DECD),                             \
                        &lds[SET][8192 + g_ * 4096 + i_ * 512]);                   \
        }                                                                          \
    } else {                                                                       \
        _Pragma("unroll") for (int g_ = 0; g_ < 3; ++g_) {                         \
            const f16* sp = whl + (size_t)(g_ * DECD + n0 + row_off) * DECD + ko_; \
            _Pragma("unroll") for (int i_ = 0; i_ < 4; ++i_)                       \
                GLOAD16(sp + (size_t)i_ * (16 * DECD),                             \
                        &lds[SET][8192 + g_ * 4096 + 2048 + i_ * 512]);            \
        }                                                                          \
    }                                                                              \
} while (0)

__global__ __launch_bounds__(256, 1)
void gru_fused(const f16* __restrict__ hch, const f16* __restrict__ hcl,
               const f16* __restrict__ whh, const f16* __restrict__ whl,
               const float* __restrict__ bhh, const float* __restrict__ gx0,
               const float* __restrict__ tg, const int* __restrict__ tseq,
               int t, f16* __restrict__ hnh, f16* __restrict__ hnl)
{
    __shared__ __align__(16) f16 lds[2][20480];   // 80 KB: {A_h, A_l, B[g][p]} x2

    const int cpx = gridDim.x >> 3;               // 1024 blocks, %8==0
    int wg = blockIdx.x;
    wg = (wg & 7) * cpx + (wg >> 3);
    const int m0 = (wg >> 4) << 7;                // 64 row-blocks of 128
    const int n0 = (wg & 15) << 6;                // 16 col-blocks of 64

    const int tid = threadIdx.x, w = tid >> 6, lane = tid & 63;
    const int wr = w >> 1, wc = w & 1;

    const int qq = (lane & 7) ^ (lane >> 3);
    const int row_off = ((lane >> 3) << 1) | (qq >> 2);
    const int k_off = (qq & 3) << 3;

    const int fr = lane & 15, kq8 = (lane >> 4) << 3;
    int offA[4], offB[2];
#pragma unroll
    for (int i = 0; i < 4; ++i) offA[i] = swz(wr * 64 + i * 16 + fr, kq8);
#pragma unroll
    for (int j = 0; j < 2; ++j) offB[j] = swz(wc * 32 + j * 16 + fr, kq8);

    f32x4 aH[3][4][2], aL[3][4][2];
#pragma unroll
    for (int g = 0; g < 3; ++g)
#pragma unroll
        for (int i = 0; i < 4; ++i)
#pragma unroll
            for (int j = 0; j < 2; ++j) { aH[g][i][j] = (f32x4)0.0f; aL[g][i][j] = (f32x4)0.0f; }

    STAGE(0, 0);
    __syncthreads();

#pragma unroll 2
    for (int kt = 0; kt < DECD / 32; ++kt) {
        const int cur = kt & 1;
        if (kt < DECD / 32 - 1) STAGE(cur ^ 1, kt + 1);

        half8 fah[4], fal[4];
#pragma unroll
        for (int i = 0; i < 4; ++i) {
            fah[i] = *(const half8*)&lds[cur][offA[i]];
            fal[i] = *(const half8*)&lds[cur][4096 + offA[i]];
        }
#pragma unroll
        for (int g = 0; g < 3; ++g) {
            half8 bh[2], bl[2];
#pragma unroll
            for (int j = 0; j < 2; ++j) {
                bh[j] = *(const half8*)&lds[cur][8192 + g * 4096 + offB[j]];
                bl[j] = *(const half8*)&lds[cur][8192 + g * 4096 + 2048 + offB[j]];
            }
#pragma unroll
            for (int i = 0; i < 4; ++i)
#pragma unroll
                for (int j = 0; j < 2; ++j) {
                    aH[g][i][j] = __builtin_amdgcn_mfma_f32_16x16x32_f16(fah[i], bh[j], aH[g][i][j], 0, 0, 0);
                    aL[g][i][j] = __builtin_amdgcn_mfma_f32_16x16x32_f16(fal[i], bh[j], aL[g][i][j], 0, 0, 0);
                    aL[g][i][j] = __builtin_amdgcn_mfma_f32_16x16x32_f16(fah[i], bl[j], aL[g][i][j], 0, 0, 0);
                }
        }
        __syncthreads();
    }

    // ---- epilogue: gate math + h update ----
    const float inv = 4.8828125e-4f;
    const int fq = lane >> 4;
    float br[2], bz[2], bn[2];
#pragma unroll
    for (int j = 0; j < 2; ++j) {
        const int col = n0 + wc * 32 + j * 16 + fr;
        br[j] = bhh[col];
        bz[j] = bhh[DECD + col];
        bn[j] = bhh[2 * DECD + col];
    }
#pragma unroll
    for (int i = 0; i < 4; ++i) {
#pragma unroll
        for (int r = 0; r < 4; ++r) {
            const int row = m0 + wr * 64 + i * 16 + fq * 4 + r;
            const int tok = (t == 0) ? SOS_TOK : tseq[(size_t)row * TLEN + (t - 1)];
            const size_t gb = (size_t)row * G3;
            const size_t tb = (size_t)tok * G3;
#pragma unroll
            for (int j = 0; j < 2; ++j) {
                const int col = n0 + wc * 32 + j * 16 + fr;
                const float ghr = aH[0][i][j][r] + aL[0][i][j][r] * inv + br[j];
                const float ghz = aH[1][i][j][r] + aL[1][i][j][r] * inv + bz[j];
                const float ghn = aH[2][i][j][r] + aL[2][i][j][r] * inv + bn[j];
                const float gir = gx0[gb + col] + tg[tb + col];
                const float giz = gx0[gb + DECD + col] + tg[tb + DECD + col];
                const float gin = gx0[gb + 2 * DECD + col] + tg[tb + 2 * DECD + col];
                const float rr = 1.f / (1.f + expf(-(gir + ghr)));
                const float zz = 1.f / (1.f + expf(-(giz + ghz)));
                const float nn = tanhf(gin + rr * ghn);
                const size_t hidx = (size_t)row * DECD + col;
                const float hp = join2(hch[hidx], hcl[hidx]);
                const float hv = (1.f - zz) * nn + zz * hp;
                f16 a_, b_; split2(hv, a_, b_);
                hnh[hidx] = a_;
                hnl[hidx] = b_;
            }
        }
    }
}

// ============ weight transpose + split: W[K][N] -> Wt_hi/lo [N][K] ============
__global__ __launch_bounds__(256)
void transpose_split(const float* __restrict__ Wm, f16* __restrict__ th, f16* __restrict__ tl,
                     int K, int N)
{
    __shared__ float tile[32][33];
    const int n0 = blockIdx.x << 5, k0 = blockIdx.y << 5;
    const int tx = threadIdx.x & 31, ty = threadIdx.x >> 5;
#pragma unroll
    for (int j = 0; j < 32; j += 8)
        tile[ty + j][tx] = Wm[(size_t)(k0 + ty + j) * N + n0 + tx];
    __syncthreads();
#pragma unroll
    for (int j = 0; j < 32; j += 8) {
        const float a = tile[tx][ty + j];
        f16 hh, hl; split2(a, hh, hl);
        const size_t o = (size_t)(n0 + ty + j) * K + k0 + tx;
        th[o] = hh; tl[o] = hl;
    }
}

// ============ Wp transpose+split with padding: Wp[1024][169] -> wph/wpl[176][1024] ============
__global__ __launch_bounds__(256)
void wp_split(const float* __restrict__ Wp, f16* __restrict__ wph, f16* __restrict__ wpl)
{
    const int k = blockIdx.x * 256 + threadIdx.x;
    const int n = blockIdx.y;
    const float a = (n < VOCAB) ? Wp[(size_t)k * VOCAB + n] : 0.0f;
    f16 h, l; split2(a, h, l);
    wph[(size_t)n * DECD + k] = h;
    wpl[(size_t)n * DECD + k] = l;
}

// ============ activation split (s input) ============
__global__ __launch_bounds__(256)
void split_act(const float* __restrict__ x, f16* __restrict__ xh, f16* __restrict__ xl)
{
    const int i = blockIdx.x * 256 + threadIdx.x;
    const float4 v = ((const float4*)x)[i];
    half4v hh, hl;
#pragma unroll
    for (int c = 0; c < 4; ++c) { f16 a, b; split2((&v.x)[c], a, b); hh[c] = a; hl[c] = b; }
    ((half4v*)xh)[i] = hh;
    ((half4v*)xl)[i] = hl;
}

// ---------------- tokgi[v] = emb[v] @ Wih[0:256, :]  ([169, 3072]) ----------------
__global__ __launch_bounds__(256)
void tok_gi(const float* __restrict__ emb, const float* __restrict__ Wih,
            float* __restrict__ tg)
{
    __shared__ float es[EMBD];
    const int v = blockIdx.y;
    const int n = blockIdx.x * 256 + threadIdx.x;
    es[threadIdx.x] = emb[(size_t)v * EMBD + threadIdx.x];
    __syncthreads();
    float s = 0.f;
#pragma unroll 8
    for (int k = 0; k < EMBD; ++k)
        s = fmaf(es[k], Wih[(size_t)k * G3 + n], s);
    tg[(size_t)v * G3 + n] = s;
}

// ---------------- MFMA logits + argmax + CE, 4-way K-split ----------------
// block = 4 waves; wave wv handles K slice [wv*256,(wv+1)*256); LDS reduce; wave0 epilogue.
__global__ __launch_bounds__(256)
void logits_mfma(const f16* __restrict__ hh, const f16* __restrict__ hl,
                 const f16* __restrict__ wph, const f16* __restrict__ wpl,
                 const float* __restrict__ bp, const int* __restrict__ tseq,
                 int t, float* __restrict__ pred, float* __restrict__ accb)
{
    __shared__ float red[3][64][44];
    const int tid = threadIdx.x, wv = tid >> 6, lane = tid & 63;
    const int b0 = blockIdx.x << 4;
    const int fr = lane & 15, kq = lane >> 4;
    const int kb = wv << 8;

    const f16* pa_h = hh + (size_t)(b0 + fr) * DECD + kb + kq * 8;
    const f16* pa_l = hl + (size_t)(b0 + fr) * DECD + kb + kq * 8;
    const f16* pb_h = wph + (size_t)fr * DECD + kb + kq * 8;
    const f16* pb_l = wpl + (size_t)fr * DECD + kb + kq * 8;

    f32x4 acch[NFRAG], accl[NFRAG];
#pragma unroll
    for (int f = 0; f < NFRAG; ++f) { acch[f] = (f32x4)0.0f; accl[f] = (f32x4)0.0f; }

#pragma unroll 2
    for (int kt = 0; kt < 8; ++kt) {
        const int ko = kt * 32;
        const half8 a_h = *(const half8*)(pa_h + ko);
        const half8 a_l = *(const half8*)(pa_l + ko);
#pragma unroll
        for (int f = 0; f < NFRAG; ++f) {
            const half8 b_h = *(const half8*)(pb_h + (size_t)f * 16 * DECD + ko);
            const half8 b_l = *(const half8*)(pb_l + (size_t)f * 16 * DECD + ko);
            acch[f] = __builtin_amdgcn_mfma_f32_16x16x32_f16(a_h, b_h, acch[f], 0, 0, 0);
            accl[f] = __builtin_amdgcn_mfma_f32_16x16x32_f16(a_l, b_h, accl[f], 0, 0, 0);
            accl[f] = __builtin_amdgcn_mfma_f32_16x16x32_f16(a_h, b_l, accl[f], 0, 0, 0);
        }
    }

    float v[44];
#pragma unroll
    for (int f = 0; f < NFRAG; ++f)
#pragma unroll
        for (int r = 0; r < 4; ++r)
            v[f * 4 + r] = acch[f][r] + accl[f][r] * 4.8828125e-4f;

    if (wv > 0) {
#pragma unroll
        for (int idx = 0; idx < 44; ++idx) red[wv - 1][lane][idx] = v[idx];
    }
    __syncthreads();
    if (wv != 0) return;

#pragma unroll
    for (int ww = 0; ww < 3; ++ww)
#pragma unroll
        for (int idx = 0; idx < 44; ++idx) v[idx] += red[ww][lane][idx];

    float wnll = 0.f, wcnt = 0.f;
#pragma unroll
    for (int r = 0; r < 4; ++r) {
        const int b = b0 + kq * 4 + r;
        float vv[NFRAG];
        float m = -3.0e38f; int mi = 0;
#pragma unroll
        for (int f = 0; f < NFRAG; ++f) {
            const int col = f * 16 + fr;
            const float bb = (col < VOCAB) ? bp[col] : -1.0e30f;
            vv[f] = v[f * 4 + r] + bb;
            if (vv[f] > m) { m = vv[f]; mi = col; }
        }
#pragma unroll
        for (int off = 8; off >= 1; off >>= 1) {
            const float om = __shfl_xor(m, off);
            const int   oi = __shfl_xor(mi, off);
            if (om > m || (om == m && oi < mi)) { m = om; mi = oi; }
        }
        const int tgt = tseq[(size_t)b * TLEN + t];
        float se = 0.f, tl = 0.f;
#pragma unroll
        for (int f = 0; f < NFRAG; ++f) {
            se += expf(vv[f] - m);
            if ((tgt >> 4) == f && (tgt & 15) == fr) tl = vv[f];
        }
#pragma unroll
        for (int off = 8; off >= 1; off >>= 1) {
            se += __shfl_xor(se, off);
            tl += __shfl_xor(tl, off);
        }
        if (fr == 0) {
            if (mi < OUTC) pred[(size_t)b * OUTC + mi] = 1.0f;
            if (tgt != IGN_TOK) { wnll += m + logf(se) - tl; wcnt += 1.f; }
        }
    }
    wnll += __shfl_xor(wnll, 16); wnll += __shfl_xor(wnll, 32);
    wcnt += __shfl_xor(wcnt, 16); wcnt += __shfl_xor(wcnt, 32);
    if (lane == 0) {
        atomicAdd(&accb[0], wnll);
        atomicAdd(&accb[1], wcnt);
    }
}

__global__ void finalize_loss(const float* __restrict__ accb, float* __restrict__ out)
{
    out[0] = accb[0] / fmaxf(accb[1], 1.f);
}

extern "C" void kernel_launch(void* const* d_in, const int* in_sizes, int n_in,
                              void* d_out, int out_size, void* d_ws, size_t ws_size,
                              hipStream_t stream)
{
    const float* s    = (const float*)d_in[0];
    const int*   aseq = (const int*)  d_in[1];
    const float* W1   = (const float*)d_in[2];
    const float* b1   = (const float*)d_in[3];
    const float* W2   = (const float*)d_in[4];
    const float* b2   = (const float*)d_in[5];
    const float* emb  = (const float*)d_in[6];
    const float* Wih  = (const float*)d_in[7];
    const float* Whh  = (const float*)d_in[8];
    const float* bih  = (const float*)d_in[9];
    const float* bhh  = (const float*)d_in[10];
    const float* Wp   = (const float*)d_in[11];
    const float* bp   = (const float*)d_in[12];
    float* outp = (float*)d_out;
    char* W = (char*)d_ws;

    // ---- arena (bytes), total ~184 MB ----
    const size_t SZ_H = (size_t)BATCH * DECD * 2;            // 16.78 MB per half
    const size_t o_gx0 = 0;                                  // [8192,3072] f32
    const size_t o_hAh = o_gx0 + (size_t)BATCH * G3 * 4;
    const size_t o_hAl = o_hAh + SZ_H;
    const size_t o_hBh = o_hAl + SZ_H;
    const size_t o_hBl = o_hBh + SZ_H;
    const size_t o_tg  = o_hBl + SZ_H;                       // [169,3072] f32
    const size_t o_whh = o_tg  + (size_t)VOCAB * G3 * 4;
    const size_t o_whl = o_whh + (size_t)DECD * G3 * 2;
    const size_t o_wph = o_whl + (size_t)DECD * G3 * 2;
    const size_t o_wpl = o_wph + (size_t)VPAD * DECD * 2;
    const size_t o_acc = o_wpl + (size_t)VPAD * DECD * 2;
    const size_t need  = o_acc + 256;
    if (ws_size < need) return;

    float* gx0  = (float*)(W + o_gx0);
    f16*   hAh  = (f16*)(W + o_hAh);
    f16*   hAl  = (f16*)(W + o_hAl);
    f16*   hBh  = (f16*)(W + o_hBh);
    f16*   hBl  = (f16*)(W + o_hBl);
    float* tg   = (float*)(W + o_tg);
    f16*   whh  = (f16*)(W + o_whh);
    f16*   whl  = (f16*)(W + o_whl);
    f16*   wph  = (f16*)(W + o_wph);
    f16*   wpl  = (f16*)(W + o_wpl);
    float* accb = (float*)(W + o_acc);

    // setup transients aliased into dead regions:
    f16* h1h = (f16*)(W + o_gx0);                                  // [8192,2048] halves in gx0
    f16* h1l = (f16*)(W + o_gx0 + (size_t)BATCH * HDIM * 2);
    f16* w1h = (f16*)(W + o_gx0 + (size_t)BATCH * HDIM * 4);       // after h1 (67.1 MB)
    f16* w1l = (f16*)(W + o_gx0 + (size_t)BATCH * HDIM * 4 + (size_t)SDIM * HDIM * 2);
    f16* w2h = w1h;                                                // w1 dead after gemm1
    f16* w2l = (f16*)(W + o_gx0 + (size_t)BATCH * HDIM * 4 + (size_t)HDIM * DECD * 2);
    f16* sh  = (f16*)(W + o_hBh);                                  // s split in h-buf B
    f16* sl  = (f16*)(W + o_hBh + (size_t)BATCH * SDIM * 2);
    f16* wih = whh;                                                // Wih^T split in whh slots
    f16* wil = whl;                                                // (overwritten by Whh later)

    hipMemsetAsync(d_out, 0, (size_t)out_size * sizeof(float), stream);
    hipMemsetAsync(accb, 0, 2 * sizeof(float), stream);

    // ---- setup ----
    split_act<<<dim3(BATCH * SDIM / 4 / 256), 256, 0, stream>>>(s, sh, sl);
    transpose_split<<<dim3(HDIM/32, SDIM/32), 256, 0, stream>>>(W1, w1h, w1l, SDIM, HDIM);
    tok_gi<<<dim3(G3/256, VOCAB), 256, 0, stream>>>(emb, Wih, tg);
    wp_split<<<dim3(DECD/256, VPAD), 256, 0, stream>>>(Wp, wph, wpl);

    // h1 = relu(s@W1+b1): split only, into gx0 region
    gemm16<2><<<dim3((BATCH/128)*(HDIM/128)), 256, 0, stream>>>(
        sh, sl, w1h, w1l, b1, nullptr, h1h, h1l, BATCH, HDIM, SDIM, 1);

    transpose_split<<<dim3(DECD/32, HDIM/32), 256, 0, stream>>>(W2, w2h, w2l, HDIM, DECD);
    // h0 = h1@W2+b2: split into h-buf A
    gemm16<2><<<dim3((BATCH/128)*(DECD/128)), 256, 0, stream>>>(
        h1h, h1l, w2h, w2l, b2, nullptr, hAh, hAl, BATCH, DECD, HDIM, 0);

    transpose_split<<<dim3(G3/32, DECD/32), 256, 0, stream>>>(Wih + (size_t)EMBD * G3, wih, wil, DECD, G3);
    // gx0 = h0@Wih[256:]+bih (overwrites dead h1/w2 transients)
    gemm16<1><<<dim3((BATCH/128)*(G3/128)), 256, 0, stream>>>(
        hAh, hAl, wih, wil, bih, gx0, nullptr, nullptr, BATCH, G3, DECD, 0);

    transpose_split<<<dim3(G3/32, DECD/32), 256, 0, stream>>>(Whh, whh, whl, DECD, G3);

    // ---- decoder loop: fused GEMM+gates, double-buffered h ----
    f16 *ch = hAh, *cl = hAl, *nh = hBh, *nl = hBl;
    for (int t = 0; t < TLEN; ++t) {
        gru_fused<<<dim3((BATCH/128)*(DECD/64)), 256, 0, stream>>>(
            ch, cl, whh, whl, bhh, gx0, tg, aseq, t, nh, nl);
        logits_mfma<<<dim3(BATCH/16), 256, 0, stream>>>(
            nh, nl, wph, wpl, bp, aseq, t, outp + 1, accb);
        f16* tmp;
        tmp = ch; ch = nh; nh = tmp;
        tmp = cl; cl = nl; nl = tmp;
    }
    finalize_loss<<<1, 1, 0, stream>>>(accb, outp);
}

// Round 6
// 5951.875 us; speedup vs baseline: 2.9494x; 1.1954x over previous
//
#include <hip/hip_runtime.h>
#include <math.h>

typedef _Float16 f16;
typedef _Float16 half8 __attribute__((ext_vector_type(8)));
typedef _Float16 half4v __attribute__((ext_vector_type(4)));
typedef float f32x4 __attribute__((ext_vector_type(4)));

#define BATCH 8192
#define SDIM  1024
#define HDIM  2048
#define DECD  1024
#define EMBD  256
#define G3    3072
#define VOCAB 169
#define VPAD  176
#define NFRAG 11
#define TLEN  20
#define SOS_TOK 166
#define IGN_TOK 168
#define OUTC  166

#define GLOAD16(gp, lp) __builtin_amdgcn_global_load_lds( \
    (const __attribute__((address_space(1))) unsigned int*)(gp), \
    (__attribute__((address_space(3))) unsigned int*)(lp), 16, 0, 0)

// fp16x2 split: a ~= hi + lo/2048, avoids fp16-subnormal hi for tiny a
__device__ __forceinline__ void split2(float a, f16& h, f16& l)
{
    float hi = (fabsf(a) >= 6.103515625e-05f) ? (float)(f16)a : 0.0f;
    h = (f16)hi;
    l = (f16)((a - hi) * 2048.0f);
}

__device__ __forceinline__ float join2(f16 h, f16 l)
{
    return (float)h + (float)l * 4.8828125e-4f;
}

// LDS tile swizzle: rows paired into 128B lines, 16B slots XORed by line&7
__device__ __forceinline__ int swz(int r, int k0)   // halfword offset
{
    const int line = r >> 1;
    const int s = (((r & 1) << 2) | (k0 >> 3)) ^ (line & 7);
    return line * 64 + s * 8;
}

// ============ fp16x2 3-pass MFMA GEMM: C = op(A[M,K] @ Bt[N,K]^T + bias) ============
// MODE bit0: write fp32 C; bit1: write split (Ch, Cl)
template<int MODE>
__global__ __launch_bounds__(256, 2)
void gemm16(const f16* __restrict__ Ah, const f16* __restrict__ Al,
            const f16* __restrict__ Bh, const f16* __restrict__ Bl,
            const float* __restrict__ bias, float* __restrict__ C,
            f16* __restrict__ Ch, f16* __restrict__ Cl,
            int M, int N, int K, int relu)
{
    __shared__ __align__(16) f16 lds[4][4096];   // Ahi, Alo, Bhi, Blo (8KB each)

    const int nx = N >> 7;
    const int cpx = gridDim.x >> 3;              // grids are %8==0
    int wg = blockIdx.x;
    wg = (wg & 7) * cpx + (wg >> 3);             // XCD-aware swizzle
    const int m0 = (wg / nx) << 7;
    const int n0 = (wg % nx) << 7;

    const int tid = threadIdx.x;
    const int w = tid >> 6;
    const int lane = tid & 63;
    const int wr = w >> 1, wc = w & 1;

    const int qq = (lane & 7) ^ (lane >> 3);
    const int row_off = ((lane >> 3) << 1) | (qq >> 2);
    const int k_off = (qq & 3) << 3;
    const f16* sb = (w == 0) ? Ah + (size_t)m0 * K
                  : (w == 1) ? Al + (size_t)m0 * K
                  : (w == 2) ? Bh + (size_t)n0 * K
                             : Bl + (size_t)n0 * K;
    sb += (size_t)row_off * K + k_off;
    f16* lb = &lds[w][0];

    int offA[4], offB[4];
    {
        const int fr = lane & 15, k0 = (lane >> 4) << 3;
#pragma unroll
        for (int t = 0; t < 4; ++t) {
            offA[t] = swz(wr * 64 + t * 16 + fr, k0);
            offB[t] = swz(wc * 64 + t * 16 + fr, k0);
        }
    }

    f32x4 acch[4][4], accl[4][4];
#pragma unroll
    for (int i = 0; i < 4; ++i)
#pragma unroll
        for (int j = 0; j < 4; ++j) { acch[i][j] = (f32x4)0.0f; accl[i][j] = (f32x4)0.0f; }

    const int nkt = K >> 5;
    const size_t K16 = (size_t)K * 16;
    for (int kt = 0; kt < nkt; ++kt) {
        const f16* s = sb + kt * 32;
#pragma unroll
        for (int i = 0; i < 8; ++i)
            GLOAD16(s + (size_t)i * K16, lb + i * 512);
        __syncthreads();

        half8 fah[4], fbh[4], fal[4], fbl[4];
#pragma unroll
        for (int t = 0; t < 4; ++t) {
            fah[t] = *(const half8*)&lds[0][offA[t]];
            fal[t] = *(const half8*)&lds[1][offA[t]];
            fbh[t] = *(const half8*)&lds[2][offB[t]];
            fbl[t] = *(const half8*)&lds[3][offB[t]];
        }
#pragma unroll
        for (int i = 0; i < 4; ++i)
#pragma unroll
            for (int j = 0; j < 4; ++j) {
                acch[i][j] = __builtin_amdgcn_mfma_f32_16x16x32_f16(fah[i], fbh[j], acch[i][j], 0, 0, 0);
                accl[i][j] = __builtin_amdgcn_mfma_f32_16x16x32_f16(fal[i], fbh[j], accl[i][j], 0, 0, 0);
                accl[i][j] = __builtin_amdgcn_mfma_f32_16x16x32_f16(fah[i], fbl[j], accl[i][j], 0, 0, 0);
            }
        __syncthreads();
    }

    const float inv2048 = 4.8828125e-4f;
    const int fr = lane & 15;
    const int fq = lane >> 4;
#pragma unroll
    for (int j = 0; j < 4; ++j) {
        const int col = n0 + wc * 64 + j * 16 + fr;
        const float bc = bias[col];
#pragma unroll
        for (int i = 0; i < 4; ++i) {
            const int row0 = m0 + wr * 64 + i * 16 + fq * 4;
            const f32x4 vh = acch[i][j], vl = accl[i][j];
#pragma unroll
            for (int r = 0; r < 4; ++r) {
                float v = vh[r] + vl[r] * inv2048 + bc;
                if (relu) v = fmaxf(v, 0.0f);
                const size_t o = (size_t)(row0 + r) * N + col;
                if constexpr (MODE & 1) C[o] = v;
                if constexpr (MODE & 2) { f16 hh, hl; split2(v, hh, hl); Ch[o] = hh; Cl[o] = hl; }
            }
        }
    }
}

// ============ fused decoder step v2: gh = h@Whh^T (3 gates) + GRU gate math ============
// block: 128 batch rows x 32 hidden cols (x3 gates); 4 waves (2M x 2N), wave 64x16.
// Single-buffered 28KB LDS, m97-style stage->sync->compute->sync.
// acc = 3 gates x 4 Mfrag x (hi+lo) x 4 = 96 VGPR -> 3 waves/SIMD.
#define STAGE_V2(KT) do {                                                          \
    const int ko_ = (KT) * 32 + k_off;                                             \
    if (w == 0) {                                                                  \
        const f16* sp = hch + (size_t)(m0 + row_off) * DECD + ko_;                 \
        _Pragma("unroll") for (int i_ = 0; i_ < 8; ++i_)                           \
            GLOAD16(sp + (size_t)i_ * (16 * DECD), &lds[i_ * 512]);                \
    } else if (w == 1) {                                                           \
        const f16* sp = hcl + (size_t)(m0 + row_off) * DECD + ko_;                 \
        _Pragma("unroll") for (int i_ = 0; i_ < 8; ++i_)                           \
            GLOAD16(sp + (size_t)i_ * (16 * DECD), &lds[4096 + i_ * 512]);         \
    } else if (w == 2) {                                                           \
        _Pragma("unroll") for (int g_ = 0; g_ < 3; ++g_) {                         \
            const f16* sp = whh + (size_t)(g_ * DECD + n0 + row_off) * DECD + ko_; \
            _Pragma("unroll") for (int i_ = 0; i_ < 2; ++i_)                       \
                GLOAD16(sp + (size_t)i_ * (16 * DECD),                             \
                        &lds[8192 + g_ * 1024 + i_ * 512]);                        \
        }                                                                          \
    } else {                                                                       \
        _Pragma("unroll") for (int g_ = 0; g_ < 3; ++g_) {                         \
            const f16* sp = whl + (size_t)(g_ * DECD + n0 + row_off) * DECD + ko_; \
            _Pragma("unroll") for (int i_ = 0; i_ < 2; ++i_)                       \
                GLOAD16(sp + (size_t)i_ * (16 * DECD),                             \
                        &lds[11264 + g_ * 1024 + i_ * 512]);                       \
        }                                                                          \
    }                                                                              \
} while (0)

__global__ __launch_bounds__(256, 3)
void gru_fused(const f16* __restrict__ hch, const f16* __restrict__ hcl,
               const f16* __restrict__ whh, const f16* __restrict__ whl,
               const float* __restrict__ bhh, const float* __restrict__ gx0,
               const float* __restrict__ tg, const int* __restrict__ tseq,
               int t, f16* __restrict__ hnh, f16* __restrict__ hnl)
{
    __shared__ __align__(16) f16 lds[14336];      // 28KB: A_h(8K) A_l(8K) B_h(3x2K) B_l(3x2K)

    const int cpx = gridDim.x >> 3;               // 2048 blocks, %8==0
    int wg = blockIdx.x;
    wg = (wg & 7) * cpx + (wg >> 3);
    const int m0 = (wg >> 5) << 7;                // 64 row-blocks of 128
    const int n0 = (wg & 31) << 5;                // 32 col-blocks of 32

    const int tid = threadIdx.x, w = tid >> 6, lane = tid & 63;
    const int wr = w >> 1, wc = w & 1;

    const int qq = (lane & 7) ^ (lane >> 3);
    const int row_off = ((lane >> 3) << 1) | (qq >> 2);
    const int k_off = (qq & 3) << 3;

    const int fr = lane & 15, kq8 = (lane >> 4) << 3;
    int offA[4];
#pragma unroll
    for (int i = 0; i < 4; ++i) offA[i] = swz(wr * 64 + i * 16 + fr, kq8);
    const int offB = swz(wc * 16 + fr, kq8);

    f32x4 aH[3][4], aL[3][4];
#pragma unroll
    for (int g = 0; g < 3; ++g)
#pragma unroll
        for (int i = 0; i < 4; ++i) { aH[g][i] = (f32x4)0.0f; aL[g][i] = (f32x4)0.0f; }

    for (int kt = 0; kt < DECD / 32; ++kt) {
        STAGE_V2(kt);
        __syncthreads();

        half8 fah[4], fal[4];
#pragma unroll
        for (int i = 0; i < 4; ++i) {
            fah[i] = *(const half8*)&lds[offA[i]];
            fal[i] = *(const half8*)&lds[4096 + offA[i]];
        }
#pragma unroll
        for (int g = 0; g < 3; ++g) {
            const half8 bh = *(const half8*)&lds[8192 + g * 1024 + offB];
            const half8 bl = *(const half8*)&lds[11264 + g * 1024 + offB];
#pragma unroll
            for (int i = 0; i < 4; ++i) {
                aH[g][i] = __builtin_amdgcn_mfma_f32_16x16x32_f16(fah[i], bh, aH[g][i], 0, 0, 0);
                aL[g][i] = __builtin_amdgcn_mfma_f32_16x16x32_f16(fal[i], bh, aL[g][i], 0, 0, 0);
                aL[g][i] = __builtin_amdgcn_mfma_f32_16x16x32_f16(fah[i], bl, aL[g][i], 0, 0, 0);
            }
        }
        __syncthreads();
    }

    // ---- epilogue: gate math + h update (1 col per lane) ----
    const float inv = 4.8828125e-4f;
    const int fq = lane >> 4;
    const int col = n0 + wc * 16 + fr;
    const float br = bhh[col];
    const float bz = bhh[DECD + col];
    const float bn = bhh[2 * DECD + col];
#pragma unroll
    for (int i = 0; i < 4; ++i) {
#pragma unroll
        for (int r = 0; r < 4; ++r) {
            const int row = m0 + wr * 64 + i * 16 + fq * 4 + r;
            const int tok = (t == 0) ? SOS_TOK : tseq[(size_t)row * TLEN + (t - 1)];
            const size_t gb = (size_t)row * G3;
            const size_t tb = (size_t)tok * G3;
            const float ghr = aH[0][i][r] + aL[0][i][r] * inv + br;
            const float ghz = aH[1][i][r] + aL[1][i][r] * inv + bz;
            const float ghn = aH[2][i][r] + aL[2][i][r] * inv + bn;
            const float gir = gx0[gb + col] + tg[tb + col];
            const float giz = gx0[gb + DECD + col] + tg[tb + DECD + col];
            const float gin = gx0[gb + 2 * DECD + col] + tg[tb + 2 * DECD + col];
            const float rr = 1.f / (1.f + expf(-(gir + ghr)));
            const float zz = 1.f / (1.f + expf(-(giz + ghz)));
            const float nn = tanhf(gin + rr * ghn);
            const size_t hidx = (size_t)row * DECD + col;
            const float hp = join2(hch[hidx], hcl[hidx]);
            const float hv = (1.f - zz) * nn + zz * hp;
            f16 a_, b_; split2(hv, a_, b_);
            hnh[hidx] = a_;
            hnl[hidx] = b_;
        }
    }
}

// ============ weight transpose + split: W[K][N] -> Wt_hi/lo [N][K] ============
__global__ __launch_bounds__(256)
void transpose_split(const float* __restrict__ Wm, f16* __restrict__ th, f16* __restrict__ tl,
                     int K, int N)
{
    __shared__ float tile[32][33];
    const int n0 = blockIdx.x << 5, k0 = blockIdx.y << 5;
    const int tx = threadIdx.x & 31, ty = threadIdx.x >> 5;
#pragma unroll
    for (int j = 0; j < 32; j += 8)
        tile[ty + j][tx] = Wm[(size_t)(k0 + ty + j) * N + n0 + tx];
    __syncthreads();
#pragma unroll
    for (int j = 0; j < 32; j += 8) {
        const float a = tile[tx][ty + j];
        f16 hh, hl; split2(a, hh, hl);
        const size_t o = (size_t)(n0 + ty + j) * K + k0 + tx;
        th[o] = hh; tl[o] = hl;
    }
}

// ============ Wp transpose+split with padding: Wp[1024][169] -> wph/wpl[176][1024] ============
__global__ __launch_bounds__(256)
void wp_split(const float* __restrict__ Wp, f16* __restrict__ wph, f16* __restrict__ wpl)
{
    const int k = blockIdx.x * 256 + threadIdx.x;
    const int n = blockIdx.y;
    const float a = (n < VOCAB) ? Wp[(size_t)k * VOCAB + n] : 0.0f;
    f16 h, l; split2(a, h, l);
    wph[(size_t)n * DECD + k] = h;
    wpl[(size_t)n * DECD + k] = l;
}

// ============ activation split (s input) ============
__global__ __launch_bounds__(256)
void split_act(const float* __restrict__ x, f16* __restrict__ xh, f16* __restrict__ xl)
{
    const int i = blockIdx.x * 256 + threadIdx.x;
    const float4 v = ((const float4*)x)[i];
    half4v hh, hl;
#pragma unroll
    for (int c = 0; c < 4; ++c) { f16 a, b; split2((&v.x)[c], a, b); hh[c] = a; hl[c] = b; }
    ((half4v*)xh)[i] = hh;
    ((half4v*)xl)[i] = hl;
}

// ---------------- tokgi[v] = emb[v] @ Wih[0:256, :]  ([169, 3072]) ----------------
__global__ __launch_bounds__(256)
void tok_gi(const float* __restrict__ emb, const float* __restrict__ Wih,
            float* __restrict__ tg)
{
    __shared__ float es[EMBD];
    const int v = blockIdx.y;
    const int n = blockIdx.x * 256 + threadIdx.x;
    es[threadIdx.x] = emb[(size_t)v * EMBD + threadIdx.x];
    __syncthreads();
    float s = 0.f;
#pragma unroll 8
    for (int k = 0; k < EMBD; ++k)
        s = fmaf(es[k], Wih[(size_t)k * G3 + n], s);
    tg[(size_t)v * G3 + n] = s;
}

// ---------------- MFMA logits + argmax + CE, 4-way K-split ----------------
__global__ __launch_bounds__(256)
void logits_mfma(const f16* __restrict__ hh, const f16* __restrict__ hl,
                 const f16* __restrict__ wph, const f16* __restrict__ wpl,
                 const float* __restrict__ bp, const int* __restrict__ tseq,
                 int t, float* __restrict__ pred, float* __restrict__ accb)
{
    __shared__ float red[3][64][44];
    const int tid = threadIdx.x, wv = tid >> 6, lane = tid & 63;
    const int b0 = blockIdx.x << 4;
    const int fr = lane & 15, kq = lane >> 4;
    const int kb = wv << 8;

    const f16* pa_h = hh + (size_t)(b0 + fr) * DECD + kb + kq * 8;
    const f16* pa_l = hl + (size_t)(b0 + fr) * DECD + kb + kq * 8;
    const f16* pb_h = wph + (size_t)fr * DECD + kb + kq * 8;
    const f16* pb_l = wpl + (size_t)fr * DECD + kb + kq * 8;

    f32x4 acch[NFRAG], accl[NFRAG];
#pragma unroll
    for (int f = 0; f < NFRAG; ++f) { acch[f] = (f32x4)0.0f; accl[f] = (f32x4)0.0f; }

#pragma unroll 2
    for (int kt = 0; kt < 8; ++kt) {
        const int ko = kt * 32;
        const half8 a_h = *(const half8*)(pa_h + ko);
        const half8 a_l = *(const half8*)(pa_l + ko);
#pragma unroll
        for (int f = 0; f < NFRAG; ++f) {
            const half8 b_h = *(const half8*)(pb_h + (size_t)f * 16 * DECD + ko);
            const half8 b_l = *(const half8*)(pb_l + (size_t)f * 16 * DECD + ko);
            acch[f] = __builtin_amdgcn_mfma_f32_16x16x32_f16(a_h, b_h, acch[f], 0, 0, 0);
            accl[f] = __builtin_amdgcn_mfma_f32_16x16x32_f16(a_l, b_h, accl[f], 0, 0, 0);
            accl[f] = __builtin_amdgcn_mfma_f32_16x16x32_f16(a_h, b_l, accl[f], 0, 0, 0);
        }
    }

    float v[44];
#pragma unroll
    for (int f = 0; f < NFRAG; ++f)
#pragma unroll
        for (int r = 0; r < 4; ++r)
            v[f * 4 + r] = acch[f][r] + accl[f][r] * 4.8828125e-4f;

    if (wv > 0) {
#pragma unroll
        for (int idx = 0; idx < 44; ++idx) red[wv - 1][lane][idx] = v[idx];
    }
    __syncthreads();
    if (wv != 0) return;

#pragma unroll
    for (int ww = 0; ww < 3; ++ww)
#pragma unroll
        for (int idx = 0; idx < 44; ++idx) v[idx] += red[ww][lane][idx];

    float wnll = 0.f, wcnt = 0.f;
#pragma unroll
    for (int r = 0; r < 4; ++r) {
        const int b = b0 + kq * 4 + r;
        float vv[NFRAG];
        float m = -3.0e38f; int mi = 0;
#pragma unroll
        for (int f = 0; f < NFRAG; ++f) {
            const int col = f * 16 + fr;
            const float bb = (col < VOCAB) ? bp[col] : -1.0e30f;
            vv[f] = v[f * 4 + r] + bb;
            if (vv[f] > m) { m = vv[f]; mi = col; }
        }
#pragma unroll
        for (int off = 8; off >= 1; off >>= 1) {
            const float om = __shfl_xor(m, off);
            const int   oi = __shfl_xor(mi, off);
            if (om > m || (om == m && oi < mi)) { m = om; mi = oi; }
        }
        const int tgt = tseq[(size_t)b * TLEN + t];
        float se = 0.f, tl = 0.f;
#pragma unroll
        for (int f = 0; f < NFRAG; ++f) {
            se += expf(vv[f] - m);
            if ((tgt >> 4) == f && (tgt & 15) == fr) tl = vv[f];
        }
#pragma unroll
        for (int off = 8; off >= 1; off >>= 1) {
            se += __shfl_xor(se, off);
            tl += __shfl_xor(tl, off);
        }
        if (fr == 0) {
            if (mi < OUTC) pred[(size_t)b * OUTC + mi] = 1.0f;
            if (tgt != IGN_TOK) { wnll += m + logf(se) - tl; wcnt += 1.f; }
        }
    }
    wnll += __shfl_xor(wnll, 16); wnll += __shfl_xor(wnll, 32);
    wcnt += __shfl_xor(wcnt, 16); wcnt += __shfl_xor(wcnt, 32);
    if (lane == 0) {
        atomicAdd(&accb[0], wnll);
        atomicAdd(&accb[1], wcnt);
    }
}

__global__ void finalize_loss(const float* __restrict__ accb, float* __restrict__ out)
{
    out[0] = accb[0] / fmaxf(accb[1], 1.f);
}

extern "C" void kernel_launch(void* const* d_in, const int* in_sizes, int n_in,
                              void* d_out, int out_size, void* d_ws, size_t ws_size,
                              hipStream_t stream)
{
    const float* s    = (const float*)d_in[0];
    const int*   aseq = (const int*)  d_in[1];
    const float* W1   = (const float*)d_in[2];
    const float* b1   = (const float*)d_in[3];
    const float* W2   = (const float*)d_in[4];
    const float* b2   = (const float*)d_in[5];
    const float* emb  = (const float*)d_in[6];
    const float* Wih  = (const float*)d_in[7];
    const float* Whh  = (const float*)d_in[8];
    const float* bih  = (const float*)d_in[9];
    const float* bhh  = (const float*)d_in[10];
    const float* Wp   = (const float*)d_in[11];
    const float* bp   = (const float*)d_in[12];
    float* outp = (float*)d_out;
    char* W = (char*)d_ws;

    // ---- arena (bytes), total ~134 MB ----
    const size_t SZ_H = (size_t)BATCH * DECD * 2;            // 16.78 MB per half
    const size_t o_gx0 = 0;                                  // [8192,3072] f32
    const size_t o_hAh = o_gx0 + (size_t)BATCH * G3 * 4;
    const size_t o_hAl = o_hAh + SZ_H;
    const size_t o_hBh = o_hAl + SZ_H;
    const size_t o_hBl = o_hBh + SZ_H;
    const size_t o_tg  = o_hBl + SZ_H;                       // [169,3072] f32
    const size_t o_whh = o_tg  + (size_t)VOCAB * G3 * 4;
    const size_t o_whl = o_whh + (size_t)DECD * G3 * 2;
    const size_t o_wph = o_whl + (size_t)DECD * G3 * 2;
    const size_t o_wpl = o_wph + (size_t)VPAD * DECD * 2;
    const size_t o_acc = o_wpl + (size_t)VPAD * DECD * 2;
    const size_t need  = o_acc + 256;
    if (ws_size < need) return;

    float* gx0  = (float*)(W + o_gx0);
    f16*   hAh  = (f16*)(W + o_hAh);
    f16*   hAl  = (f16*)(W + o_hAl);
    f16*   hBh  = (f16*)(W + o_hBh);
    f16*   hBl  = (f16*)(W + o_hBl);
    float* tg   = (float*)(W + o_tg);
    f16*   whh  = (f16*)(W + o_whh);
    f16*   whl  = (f16*)(W + o_whl);
    f16*   wph  = (f16*)(W + o_wph);
    f16*   wpl  = (f16*)(W + o_wpl);
    float* accb = (float*)(W + o_acc);

    // setup transients aliased into dead regions:
    f16* h1h = (f16*)(W + o_gx0);                                  // [8192,2048] halves in gx0
    f16* h1l = (f16*)(W + o_gx0 + (size_t)BATCH * HDIM * 2);
    f16* w1h = (f16*)(W + o_gx0 + (size_t)BATCH * HDIM * 4);       // after h1 (67.1 MB)
    f16* w1l = (f16*)(W + o_gx0 + (size_t)BATCH * HDIM * 4 + (size_t)SDIM * HDIM * 2);
    f16* w2h = w1h;                                                // w1 dead after gemm1
    f16* w2l = (f16*)(W + o_gx0 + (size_t)BATCH * HDIM * 4 + (size_t)HDIM * DECD * 2);
    f16* sh  = (f16*)(W + o_hBh);                                  // s split in h-buf B
    f16* sl  = (f16*)(W + o_hBh + (size_t)BATCH * SDIM * 2);
    f16* wih = whh;                                                // Wih^T split in whh slots
    f16* wil = whl;                                                // (overwritten by Whh later)

    hipMemsetAsync(d_out, 0, (size_t)out_size * sizeof(float), stream);
    hipMemsetAsync(accb, 0, 2 * sizeof(float), stream);

    // ---- setup ----
    split_act<<<dim3(BATCH * SDIM / 4 / 256), 256, 0, stream>>>(s, sh, sl);
    transpose_split<<<dim3(HDIM/32, SDIM/32), 256, 0, stream>>>(W1, w1h, w1l, SDIM, HDIM);
    tok_gi<<<dim3(G3/256, VOCAB), 256, 0, stream>>>(emb, Wih, tg);
    wp_split<<<dim3(DECD/256, VPAD), 256, 0, stream>>>(Wp, wph, wpl);

    // h1 = relu(s@W1+b1): split only, into gx0 region
    gemm16<2><<<dim3((BATCH/128)*(HDIM/128)), 256, 0, stream>>>(
        sh, sl, w1h, w1l, b1, nullptr, h1h, h1l, BATCH, HDIM, SDIM, 1);

    transpose_split<<<dim3(DECD/32, HDIM/32), 256, 0, stream>>>(W2, w2h, w2l, HDIM, DECD);
    // h0 = h1@W2+b2: split into h-buf A
    gemm16<2><<<dim3((BATCH/128)*(DECD/128)), 256, 0, stream>>>(
        h1h, h1l, w2h, w2l, b2, nullptr, hAh, hAl, BATCH, DECD, HDIM, 0);

    transpose_split<<<dim3(G3/32, DECD/32), 256, 0, stream>>>(Wih + (size_t)EMBD * G3, wih, wil, DECD, G3);
    // gx0 = h0@Wih[256:]+bih (overwrites dead h1/w2 transients)
    gemm16<1><<<dim3((BATCH/128)*(G3/128)), 256, 0, stream>>>(
        hAh, hAl, wih, wil, bih, gx0, nullptr, nullptr, BATCH, G3, DECD, 0);

    transpose_split<<<dim3(G3/32, DECD/32), 256, 0, stream>>>(Whh, whh, whl, DECD, G3);

    // ---- decoder loop: fused GEMM+gates, double-buffered h ----
    f16 *ch = hAh, *cl = hAl, *nh = hBh, *nl = hBl;
    for (int t = 0; t < TLEN; ++t) {
        gru_fused<<<dim3((BATCH/128)*(DECD/32)), 256, 0, stream>>>(
            ch, cl, whh, whl, bhh, gx0, tg, aseq, t, nh, nl);
        logits_mfma<<<dim3(BATCH/16), 256, 0, stream>>>(
            nh, nl, wph, wpl, bp, aseq, t, outp + 1, accb);
        f16* tmp;
        tmp = ch; ch = nh; nh = tmp;
        tmp = cl; cl = nl; nl = tmp;
    }
    finalize_loss<<<1, 1, 0, stream>>>(accb, outp);
}

// Round 7
// 5722.385 us; speedup vs baseline: 3.0677x; 1.0401x over previous
//
#include <hip/hip_runtime.h>
#include <math.h>

typedef _Float16 f16;
typedef _Float16 half8 __attribute__((ext_vector_type(8)));
typedef _Float16 half4v __attribute__((ext_vector_type(4)));
typedef float f32x4 __attribute__((ext_vector_type(4)));

#define BATCH 8192
#define SDIM  1024
#define HDIM  2048
#define DECD  1024
#define EMBD  256
#define G3    3072
#define VOCAB 169
#define VPAD  176
#define NFRAG 11
#define TLEN  20
#define SOS_TOK 166
#define IGN_TOK 168
#define OUTC  166

#define GLOAD16(gp, lp) __builtin_amdgcn_global_load_lds( \
    (const __attribute__((address_space(1))) unsigned int*)(gp), \
    (__attribute__((address_space(3))) unsigned int*)(lp), 16, 0, 0)

// fp16x2 split: a ~= hi + lo/2048, avoids fp16-subnormal hi for tiny a
__device__ __forceinline__ void split2(float a, f16& h, f16& l)
{
    float hi = (fabsf(a) >= 6.103515625e-05f) ? (float)(f16)a : 0.0f;
    h = (f16)hi;
    l = (f16)((a - hi) * 2048.0f);
}

__device__ __forceinline__ float join2(f16 h, f16 l)
{
    return (float)h + (float)l * 4.8828125e-4f;
}

// LDS tile swizzle: rows paired into 128B lines, 16B slots XORed by line&7
__device__ __forceinline__ int swz(int r, int k0)   // halfword offset
{
    const int line = r >> 1;
    const int s = (((r & 1) << 2) | (k0 >> 3)) ^ (line & 7);
    return line * 64 + s * 8;
}

// ============ fp16x2 3-pass MFMA GEMM: C = op(A[M,K] @ Bt[N,K]^T + bias) ============
// MODE bit0: write fp32 C; bit1: write split (Ch, Cl)
template<int MODE>
__global__ __launch_bounds__(256, 2)
void gemm16(const f16* __restrict__ Ah, const f16* __restrict__ Al,
            const f16* __restrict__ Bh, const f16* __restrict__ Bl,
            const float* __restrict__ bias, float* __restrict__ C,
            f16* __restrict__ Ch, f16* __restrict__ Cl,
            int M, int N, int K, int relu)
{
    __shared__ __align__(16) f16 lds[4][4096];   // Ahi, Alo, Bhi, Blo (8KB each)

    const int nx = N >> 7;
    const int cpx = gridDim.x >> 3;              // grids are %8==0
    int wg = blockIdx.x;
    wg = (wg & 7) * cpx + (wg >> 3);             // XCD-aware swizzle
    const int m0 = (wg / nx) << 7;
    const int n0 = (wg % nx) << 7;

    const int tid = threadIdx.x;
    const int w = tid >> 6;
    const int lane = tid & 63;
    const int wr = w >> 1, wc = w & 1;

    const int qq = (lane & 7) ^ (lane >> 3);
    const int row_off = ((lane >> 3) << 1) | (qq >> 2);
    const int k_off = (qq & 3) << 3;
    const f16* sb = (w == 0) ? Ah + (size_t)m0 * K
                  : (w == 1) ? Al + (size_t)m0 * K
                  : (w == 2) ? Bh + (size_t)n0 * K
                             : Bl + (size_t)n0 * K;
    sb += (size_t)row_off * K + k_off;
    f16* lb = &lds[w][0];

    int offA[4], offB[4];
    {
        const int fr = lane & 15, k0 = (lane >> 4) << 3;
#pragma unroll
        for (int t = 0; t < 4; ++t) {
            offA[t] = swz(wr * 64 + t * 16 + fr, k0);
            offB[t] = swz(wc * 64 + t * 16 + fr, k0);
        }
    }

    f32x4 acch[4][4], accl[4][4];
#pragma unroll
    for (int i = 0; i < 4; ++i)
#pragma unroll
        for (int j = 0; j < 4; ++j) { acch[i][j] = (f32x4)0.0f; accl[i][j] = (f32x4)0.0f; }

    const int nkt = K >> 5;
    const size_t K16 = (size_t)K * 16;
    for (int kt = 0; kt < nkt; ++kt) {
        const f16* s = sb + kt * 32;
#pragma unroll
        for (int i = 0; i < 8; ++i)
            GLOAD16(s + (size_t)i * K16, lb + i * 512);
        __syncthreads();

        half8 fah[4], fbh[4], fal[4], fbl[4];
#pragma unroll
        for (int t = 0; t < 4; ++t) {
            fah[t] = *(const half8*)&lds[0][offA[t]];
            fal[t] = *(const half8*)&lds[1][offA[t]];
            fbh[t] = *(const half8*)&lds[2][offB[t]];
            fbl[t] = *(const half8*)&lds[3][offB[t]];
        }
#pragma unroll
        for (int i = 0; i < 4; ++i)
#pragma unroll
            for (int j = 0; j < 4; ++j) {
                acch[i][j] = __builtin_amdgcn_mfma_f32_16x16x32_f16(fah[i], fbh[j], acch[i][j], 0, 0, 0);
                accl[i][j] = __builtin_amdgcn_mfma_f32_16x16x32_f16(fal[i], fbh[j], accl[i][j], 0, 0, 0);
                accl[i][j] = __builtin_amdgcn_mfma_f32_16x16x32_f16(fah[i], fbl[j], accl[i][j], 0, 0, 0);
            }
        __syncthreads();
    }

    const float inv2048 = 4.8828125e-4f;
    const int fr = lane & 15;
    const int fq = lane >> 4;
#pragma unroll
    for (int j = 0; j < 4; ++j) {
        const int col = n0 + wc * 64 + j * 16 + fr;
        const float bc = bias[col];
#pragma unroll
        for (int i = 0; i < 4; ++i) {
            const int row0 = m0 + wr * 64 + i * 16 + fq * 4;
            const f32x4 vh = acch[i][j], vl = accl[i][j];
#pragma unroll
            for (int r = 0; r < 4; ++r) {
                float v = vh[r] + vl[r] * inv2048 + bc;
                if (relu) v = fmaxf(v, 0.0f);
                const size_t o = (size_t)(row0 + r) * N + col;
                if constexpr (MODE & 1) C[o] = v;
                if constexpr (MODE & 2) { f16 hh, hl; split2(v, hh, hl); Ch[o] = hh; Cl[o] = hl; }
            }
        }
    }
}

// ============ fused decoder step v3: gh = h@Whh^T (3 gates) + GRU gate math ============
// block: 128 batch rows x 32 hidden cols (x3 gates); 4 waves (2M x 2N), wave 64x16.
// Single-buffered 28KB LDS, m97-style stage->sync->compute->sync.
// XCD-pinned mapping: XCD k (= blockIdx%8) owns col-strips [4k,4k+4) x all 64 row
// tiles, row-major -> weight working set 1.57MB stays L2-resident per XCD, and
// each A-tile (h rows) is reused 4x back-to-back.
#define STAGE_V2(KT) do {                                                          \
    const int ko_ = (KT) * 32 + k_off;                                             \
    if (w == 0) {                                                                  \
        const f16* sp = hch + (size_t)(m0 + row_off) * DECD + ko_;                 \
        _Pragma("unroll") for (int i_ = 0; i_ < 8; ++i_)                           \
            GLOAD16(sp + (size_t)i_ * (16 * DECD), &lds[i_ * 512]);                \
    } else if (w == 1) {                                                           \
        const f16* sp = hcl + (size_t)(m0 + row_off) * DECD + ko_;                 \
        _Pragma("unroll") for (int i_ = 0; i_ < 8; ++i_)                           \
            GLOAD16(sp + (size_t)i_ * (16 * DECD), &lds[4096 + i_ * 512]);         \
    } else if (w == 2) {                                                           \
        _Pragma("unroll") for (int g_ = 0; g_ < 3; ++g_) {                         \
            const f16* sp = whh + (size_t)(g_ * DECD + n0 + row_off) * DECD + ko_; \
            _Pragma("unroll") for (int i_ = 0; i_ < 2; ++i_)                       \
                GLOAD16(sp + (size_t)i_ * (16 * DECD),                             \
                        &lds[8192 + g_ * 1024 + i_ * 512]);                        \
        }                                                                          \
    } else {                                                                       \
        _Pragma("unroll") for (int g_ = 0; g_ < 3; ++g_) {                         \
            const f16* sp = whl + (size_t)(g_ * DECD + n0 + row_off) * DECD + ko_; \
            _Pragma("unroll") for (int i_ = 0; i_ < 2; ++i_)                       \
                GLOAD16(sp + (size_t)i_ * (16 * DECD),                             \
                        &lds[11264 + g_ * 1024 + i_ * 512]);                       \
        }                                                                          \
    }                                                                              \
} while (0)

__global__ __launch_bounds__(256, 3)
void gru_fused(const f16* __restrict__ hch, const f16* __restrict__ hcl,
               const f16* __restrict__ whh, const f16* __restrict__ whl,
               const float* __restrict__ bhh, const float* __restrict__ gx0,
               const float* __restrict__ tg, const int* __restrict__ tseq,
               int t, f16* __restrict__ hnh, f16* __restrict__ hnl)
{
    __shared__ __align__(16) f16 lds[14336];      // 28KB: A_h(8K) A_l(8K) B_h(3x2K) B_l(3x2K)

    // XCD-pinned decomposition (grid 2048 = 8 chunks x 64 rows x 4 strips)
    const int chunk = blockIdx.x & 7;             // -> XCD (HW round-robin)
    const int q     = blockIdx.x >> 3;            // 0..255, row-major within chunk
    const int m0 = (q >> 2) << 7;                 // 64 row-tiles of 128
    const int n0 = (chunk * 4 + (q & 3)) << 5;    // 4 col-strips of 32 per XCD

    const int tid = threadIdx.x, w = tid >> 6, lane = tid & 63;
    const int wr = w >> 1, wc = w & 1;

    const int qq = (lane & 7) ^ (lane >> 3);
    const int row_off = ((lane >> 3) << 1) | (qq >> 2);
    const int k_off = (qq & 3) << 3;

    const int fr = lane & 15, kq8 = (lane >> 4) << 3;
    int offA[4];
#pragma unroll
    for (int i = 0; i < 4; ++i) offA[i] = swz(wr * 64 + i * 16 + fr, kq8);
    const int offB = swz(wc * 16 + fr, kq8);

    f32x4 aH[3][4], aL[3][4];
#pragma unroll
    for (int g = 0; g < 3; ++g)
#pragma unroll
        for (int i = 0; i < 4; ++i) { aH[g][i] = (f32x4)0.0f; aL[g][i] = (f32x4)0.0f; }

    for (int kt = 0; kt < DECD / 32; ++kt) {
        STAGE_V2(kt);
        __syncthreads();

        half8 fah[4], fal[4];
#pragma unroll
        for (int i = 0; i < 4; ++i) {
            fah[i] = *(const half8*)&lds[offA[i]];
            fal[i] = *(const half8*)&lds[4096 + offA[i]];
        }
#pragma unroll
        for (int g = 0; g < 3; ++g) {
            const half8 bh = *(const half8*)&lds[8192 + g * 1024 + offB];
            const half8 bl = *(const half8*)&lds[11264 + g * 1024 + offB];
#pragma unroll
            for (int i = 0; i < 4; ++i) {
                aH[g][i] = __builtin_amdgcn_mfma_f32_16x16x32_f16(fah[i], bh, aH[g][i], 0, 0, 0);
                aL[g][i] = __builtin_amdgcn_mfma_f32_16x16x32_f16(fal[i], bh, aL[g][i], 0, 0, 0);
                aL[g][i] = __builtin_amdgcn_mfma_f32_16x16x32_f16(fah[i], bl, aL[g][i], 0, 0, 0);
            }
        }
        __syncthreads();
    }

    // ---- epilogue: gate math + h update (1 col per lane) ----
    const float inv = 4.8828125e-4f;
    const int fq = lane >> 4;
    const int col = n0 + wc * 16 + fr;
    const float br = bhh[col];
    const float bz = bhh[DECD + col];
    const float bn = bhh[2 * DECD + col];
#pragma unroll
    for (int i = 0; i < 4; ++i) {
#pragma unroll
        for (int r = 0; r < 4; ++r) {
            const int row = m0 + wr * 64 + i * 16 + fq * 4 + r;
            const int tok = (t == 0) ? SOS_TOK : tseq[(size_t)row * TLEN + (t - 1)];
            const size_t gb = (size_t)row * G3;
            const size_t tb = (size_t)tok * G3;
            const float ghr = aH[0][i][r] + aL[0][i][r] * inv + br;
            const float ghz = aH[1][i][r] + aL[1][i][r] * inv + bz;
            const float ghn = aH[2][i][r] + aL[2][i][r] * inv + bn;
            const float gir = gx0[gb + col] + tg[tb + col];
            const float giz = gx0[gb + DECD + col] + tg[tb + DECD + col];
            const float gin = gx0[gb + 2 * DECD + col] + tg[tb + 2 * DECD + col];
            const float rr = 1.f / (1.f + expf(-(gir + ghr)));
            const float zz = 1.f / (1.f + expf(-(giz + ghz)));
            const float nn = tanhf(gin + rr * ghn);
            const size_t hidx = (size_t)row * DECD + col;
            const float hp = join2(hch[hidx], hcl[hidx]);
            const float hv = (1.f - zz) * nn + zz * hp;
            f16 a_, b_; split2(hv, a_, b_);
            hnh[hidx] = a_;
            hnl[hidx] = b_;
        }
    }
}

// ============ weight transpose + split: W[K][N] -> Wt_hi/lo [N][K] ============
__global__ __launch_bounds__(256)
void transpose_split(const float* __restrict__ Wm, f16* __restrict__ th, f16* __restrict__ tl,
                     int K, int N)
{
    __shared__ float tile[32][33];
    const int n0 = blockIdx.x << 5, k0 = blockIdx.y << 5;
    const int tx = threadIdx.x & 31, ty = threadIdx.x >> 5;
#pragma unroll
    for (int j = 0; j < 32; j += 8)
        tile[ty + j][tx] = Wm[(size_t)(k0 + ty + j) * N + n0 + tx];
    __syncthreads();
#pragma unroll
    for (int j = 0; j < 32; j += 8) {
        const float a = tile[tx][ty + j];
        f16 hh, hl; split2(a, hh, hl);
        const size_t o = (size_t)(n0 + ty + j) * K + k0 + tx;
        th[o] = hh; tl[o] = hl;
    }
}

// ============ Wp transpose+split with padding: Wp[1024][169] -> wph/wpl[176][1024] ============
__global__ __launch_bounds__(256)
void wp_split(const float* __restrict__ Wp, f16* __restrict__ wph, f16* __restrict__ wpl)
{
    const int k = blockIdx.x * 256 + threadIdx.x;
    const int n = blockIdx.y;
    const float a = (n < VOCAB) ? Wp[(size_t)k * VOCAB + n] : 0.0f;
    f16 h, l; split2(a, h, l);
    wph[(size_t)n * DECD + k] = h;
    wpl[(size_t)n * DECD + k] = l;
}

// ============ activation split (s input) ============
__global__ __launch_bounds__(256)
void split_act(const float* __restrict__ x, f16* __restrict__ xh, f16* __restrict__ xl)
{
    const int i = blockIdx.x * 256 + threadIdx.x;
    const float4 v = ((const float4*)x)[i];
    half4v hh, hl;
#pragma unroll
    for (int c = 0; c < 4; ++c) { f16 a, b; split2((&v.x)[c], a, b); hh[c] = a; hl[c] = b; }
    ((half4v*)xh)[i] = hh;
    ((half4v*)xl)[i] = hl;
}

// ---------------- tokgi[v] = emb[v] @ Wih[0:256, :]  ([169, 3072]) ----------------
__global__ __launch_bounds__(256)
void tok_gi(const float* __restrict__ emb, const float* __restrict__ Wih,
            float* __restrict__ tg)
{
    __shared__ float es[EMBD];
    const int v = blockIdx.y;
    const int n = blockIdx.x * 256 + threadIdx.x;
    es[threadIdx.x] = emb[(size_t)v * EMBD + threadIdx.x];
    __syncthreads();
    float s = 0.f;
#pragma unroll 8
    for (int k = 0; k < EMBD; ++k)
        s = fmaf(es[k], Wih[(size_t)k * G3 + n], s);
    tg[(size_t)v * G3 + n] = s;
}

// ---------------- MFMA logits + argmax + CE, 4-way K-split ----------------
__global__ __launch_bounds__(256)
void logits_mfma(const f16* __restrict__ hh, const f16* __restrict__ hl,
                 const f16* __restrict__ wph, const f16* __restrict__ wpl,
                 const float* __restrict__ bp, const int* __restrict__ tseq,
                 int t, float* __restrict__ pred, float* __restrict__ accb)
{
    __shared__ float red[3][64][44];
    const int tid = threadIdx.x, wv = tid >> 6, lane = tid & 63;
    const int b0 = blockIdx.x << 4;
    const int fr = lane & 15, kq = lane >> 4;
    const int kb = wv << 8;

    const f16* pa_h = hh + (size_t)(b0 + fr) * DECD + kb + kq * 8;
    const f16* pa_l = hl + (size_t)(b0 + fr) * DECD + kb + kq * 8;
    const f16* pb_h = wph + (size_t)fr * DECD + kb + kq * 8;
    const f16* pb_l = wpl + (size_t)fr * DECD + kb + kq * 8;

    f32x4 acch[NFRAG], accl[NFRAG];
#pragma unroll
    for (int f = 0; f < NFRAG; ++f) { acch[f] = (f32x4)0.0f; accl[f] = (f32x4)0.0f; }

#pragma unroll 2
    for (int kt = 0; kt < 8; ++kt) {
        const int ko = kt * 32;
        const half8 a_h = *(const half8*)(pa_h + ko);
        const half8 a_l = *(const half8*)(pa_l + ko);
#pragma unroll
        for (int f = 0; f < NFRAG; ++f) {
            const half8 b_h = *(const half8*)(pb_h + (size_t)f * 16 * DECD + ko);
            const half8 b_l = *(const half8*)(pb_l + (size_t)f * 16 * DECD + ko);
            acch[f] = __builtin_amdgcn_mfma_f32_16x16x32_f16(a_h, b_h, acch[f], 0, 0, 0);
            accl[f] = __builtin_amdgcn_mfma_f32_16x16x32_f16(a_l, b_h, accl[f], 0, 0, 0);
            accl[f] = __builtin_amdgcn_mfma_f32_16x16x32_f16(a_h, b_l, accl[f], 0, 0, 0);
        }
    }

    float v[44];
#pragma unroll
    for (int f = 0; f < NFRAG; ++f)
#pragma unroll
        for (int r = 0; r < 4; ++r)
            v[f * 4 + r] = acch[f][r] + accl[f][r] * 4.8828125e-4f;

    if (wv > 0) {
#pragma unroll
        for (int idx = 0; idx < 44; ++idx) red[wv - 1][lane][idx] = v[idx];
    }
    __syncthreads();
    if (wv != 0) return;

#pragma unroll
    for (int ww = 0; ww < 3; ++ww)
#pragma unroll
        for (int idx = 0; idx < 44; ++idx) v[idx] += red[ww][lane][idx];

    float wnll = 0.f, wcnt = 0.f;
#pragma unroll
    for (int r = 0; r < 4; ++r) {
        const int b = b0 + kq * 4 + r;
        float vv[NFRAG];
        float m = -3.0e38f; int mi = 0;
#pragma unroll
        for (int f = 0; f < NFRAG; ++f) {
            const int col = f * 16 + fr;
            const float bb = (col < VOCAB) ? bp[col] : -1.0e30f;
            vv[f] = v[f * 4 + r] + bb;
            if (vv[f] > m) { m = vv[f]; mi = col; }
        }
#pragma unroll
        for (int off = 8; off >= 1; off >>= 1) {
            const float om = __shfl_xor(m, off);
            const int   oi = __shfl_xor(mi, off);
            if (om > m || (om == m && oi < mi)) { m = om; mi = oi; }
        }
        const int tgt = tseq[(size_t)b * TLEN + t];
        float se = 0.f, tl = 0.f;
#pragma unroll
        for (int f = 0; f < NFRAG; ++f) {
            se += expf(vv[f] - m);
            if ((tgt >> 4) == f && (tgt & 15) == fr) tl = vv[f];
        }
#pragma unroll
        for (int off = 8; off >= 1; off >>= 1) {
            se += __shfl_xor(se, off);
            tl += __shfl_xor(tl, off);
        }
        if (fr == 0) {
            if (mi < OUTC) pred[(size_t)b * OUTC + mi] = 1.0f;
            if (tgt != IGN_TOK) { wnll += m + logf(se) - tl; wcnt += 1.f; }
        }
    }
    wnll += __shfl_xor(wnll, 16); wnll += __shfl_xor(wnll, 32);
    wcnt += __shfl_xor(wcnt, 16); wcnt += __shfl_xor(wcnt, 32);
    if (lane == 0) {
        atomicAdd(&accb[0], wnll);
        atomicAdd(&accb[1], wcnt);
    }
}

__global__ void finalize_loss(const float* __restrict__ accb, float* __restrict__ out)
{
    out[0] = accb[0] / fmaxf(accb[1], 1.f);
}

extern "C" void kernel_launch(void* const* d_in, const int* in_sizes, int n_in,
                              void* d_out, int out_size, void* d_ws, size_t ws_size,
                              hipStream_t stream)
{
    const float* s    = (const float*)d_in[0];
    const int*   aseq = (const int*)  d_in[1];
    const float* W1   = (const float*)d_in[2];
    const float* b1   = (const float*)d_in[3];
    const float* W2   = (const float*)d_in[4];
    const float* b2   = (const float*)d_in[5];
    const float* emb  = (const float*)d_in[6];
    const float* Wih  = (const float*)d_in[7];
    const float* Whh  = (const float*)d_in[8];
    const float* bih  = (const float*)d_in[9];
    const float* bhh  = (const float*)d_in[10];
    const float* Wp   = (const float*)d_in[11];
    const float* bp   = (const float*)d_in[12];
    float* outp = (float*)d_out;
    char* W = (char*)d_ws;

    // ---- arena (bytes), total ~134 MB ----
    const size_t SZ_H = (size_t)BATCH * DECD * 2;            // 16.78 MB per half
    const size_t o_gx0 = 0;                                  // [8192,3072] f32
    const size_t o_hAh = o_gx0 + (size_t)BATCH * G3 * 4;
    const size_t o_hAl = o_hAh + SZ_H;
    const size_t o_hBh = o_hAl + SZ_H;
    const size_t o_hBl = o_hBh + SZ_H;
    const size_t o_tg  = o_hBl + SZ_H;                       // [169,3072] f32
    const size_t o_whh = o_tg  + (size_t)VOCAB * G3 * 4;
    const size_t o_whl = o_whh + (size_t)DECD * G3 * 2;
    const size_t o_wph = o_whl + (size_t)DECD * G3 * 2;
    const size_t o_wpl = o_wph + (size_t)VPAD * DECD * 2;
    const size_t o_acc = o_wpl + (size_t)VPAD * DECD * 2;
    const size_t need  = o_acc + 256;
    if (ws_size < need) return;

    float* gx0  = (float*)(W + o_gx0);
    f16*   hAh  = (f16*)(W + o_hAh);
    f16*   hAl  = (f16*)(W + o_hAl);
    f16*   hBh  = (f16*)(W + o_hBh);
    f16*   hBl  = (f16*)(W + o_hBl);
    float* tg   = (float*)(W + o_tg);
    f16*   whh  = (f16*)(W + o_whh);
    f16*   whl  = (f16*)(W + o_whl);
    f16*   wph  = (f16*)(W + o_wph);
    f16*   wpl  = (f16*)(W + o_wpl);
    float* accb = (float*)(W + o_acc);

    // setup transients aliased into dead regions:
    f16* h1h = (f16*)(W + o_gx0);                                  // [8192,2048] halves in gx0
    f16* h1l = (f16*)(W + o_gx0 + (size_t)BATCH * HDIM * 2);
    f16* w1h = (f16*)(W + o_gx0 + (size_t)BATCH * HDIM * 4);       // after h1 (67.1 MB)
    f16* w1l = (f16*)(W + o_gx0 + (size_t)BATCH * HDIM * 4 + (size_t)SDIM * HDIM * 2);
    f16* w2h = w1h;                                                // w1 dead after gemm1
    f16* w2l = (f16*)(W + o_gx0 + (size_t)BATCH * HDIM * 4 + (size_t)HDIM * DECD * 2);
    f16* sh  = (f16*)(W + o_hBh);                                  // s split in h-buf B
    f16* sl  = (f16*)(W + o_hBh + (size_t)BATCH * SDIM * 2);
    f16* wih = whh;                                                // Wih^T split in whh slots
    f16* wil = whl;                                                // (overwritten by Whh later)

    hipMemsetAsync(d_out, 0, (size_t)out_size * sizeof(float), stream);
    hipMemsetAsync(accb, 0, 2 * sizeof(float), stream);

    // ---- setup ----
    split_act<<<dim3(BATCH * SDIM / 4 / 256), 256, 0, stream>>>(s, sh, sl);
    transpose_split<<<dim3(HDIM/32, SDIM/32), 256, 0, stream>>>(W1, w1h, w1l, SDIM, HDIM);
    tok_gi<<<dim3(G3/256, VOCAB), 256, 0, stream>>>(emb, Wih, tg);
    wp_split<<<dim3(DECD/256, VPAD), 256, 0, stream>>>(Wp, wph, wpl);

    // h1 = relu(s@W1+b1): split only, into gx0 region
    gemm16<2><<<dim3((BATCH/128)*(HDIM/128)), 256, 0, stream>>>(
        sh, sl, w1h, w1l, b1, nullptr, h1h, h1l, BATCH, HDIM, SDIM, 1);

    transpose_split<<<dim3(DECD/32, HDIM/32), 256, 0, stream>>>(W2, w2h, w2l, HDIM, DECD);
    // h0 = h1@W2+b2: split into h-buf A
    gemm16<2><<<dim3((BATCH/128)*(DECD/128)), 256, 0, stream>>>(
        h1h, h1l, w2h, w2l, b2, nullptr, hAh, hAl, BATCH, DECD, HDIM, 0);

    transpose_split<<<dim3(G3/32, DECD/32), 256, 0, stream>>>(Wih + (size_t)EMBD * G3, wih, wil, DECD, G3);
    // gx0 = h0@Wih[256:]+bih (overwrites dead h1/w2 transients)
    gemm16<1><<<dim3((BATCH/128)*(G3/128)), 256, 0, stream>>>(
        hAh, hAl, wih, wil, bih, gx0, nullptr, nullptr, BATCH, G3, DECD, 0);

    transpose_split<<<dim3(G3/32, DECD/32), 256, 0, stream>>>(Whh, whh, whl, DECD, G3);

    // ---- decoder loop: fused GEMM+gates, double-buffered h ----
    f16 *ch = hAh, *cl = hAl, *nh = hBh, *nl = hBl;
    for (int t = 0; t < TLEN; ++t) {
        gru_fused<<<dim3((BATCH/128)*(DECD/32)), 256, 0, stream>>>(
            ch, cl, whh, whl, bhh, gx0, tg, aseq, t, nh, nl);
        logits_mfma<<<dim3(BATCH/16), 256, 0, stream>>>(
            nh, nl, wph, wpl, bp, aseq, t, outp + 1, accb);
        f16* tmp;
        tmp = ch; ch = nh; nh = tmp;
        tmp = cl; cl = nl; nl = tmp;
    }
    finalize_loss<<<1, 1, 0, stream>>>(accb, outp);
}